// Round 9
// baseline (855.941 us; speedup 1.0000x reference)
//
#include <hip/hip_runtime.h>
#include <math.h>

#define QLEN 1024
#define BSZ 4
#define NH 10
#define DH 38
#define DM 380
#define DI 900
#define H3 1140
#define RLEN 2049
#define RLP 2112                      // RLEN padded to 33*64
#define SCALE 0.16222142113076254f   // 1/sqrt(38)
#define KS 2                          // k-splits in attention

typedef unsigned short ushortt;
typedef __attribute__((ext_vector_type(8))) short short8;
typedef __attribute__((ext_vector_type(4))) float float4v;

__device__ __forceinline__ float bf2f(ushortt u) {
    return __uint_as_float(((unsigned int)u) << 16);
}
__device__ __forceinline__ ushortt f2bf(float f) {
    unsigned int u = __float_as_uint(f);
    u += 0x7fffu + ((u >> 16) & 1u);   // RNE
    return (ushortt)(u >> 16);
}

// ---------- f32 [R][C] -> bf16 [Rp][Cp], zero-padded ----------
__global__ __launch_bounds__(256)
void convpad(const float* __restrict__ src, ushortt* __restrict__ dst,
             int R, int C, int Rp, int Cp) {
    const int total = Rp * Cp;
    for (int i = blockIdx.x * 256 + threadIdx.x; i < total; i += gridDim.x * 256) {
        int r = i / Cp, c = i - r * Cp;
        float v = (r < R && c < C) ? src[(size_t)r * C + c] : 0.f;
        dst[i] = f2bf(v);
    }
}

// ---------- zero the pad lanes once per launch ----------
__global__ __launch_bounds__(256)
void init_pads(float* __restrict__ qwp, float* __restrict__ Kp, float* __restrict__ Vp,
               ushortt* __restrict__ vec) {
    const int i = blockIdx.x * 256 + threadIdx.x;
    if (i < BSZ * NH * 1024 * 2) {                       // d=38,39 of the head arrays
        size_t idx = (size_t)(i >> 1) * 40 + 38 + (i & 1);
        qwp[idx] = 0.f; Kp[idx] = 0.f; Vp[idx] = 0.f;
    }
    if (i < 4096 * 4) {                                  // vec cols 380..383
        vec[(size_t)(i >> 2) * 384 + 380 + (i & 3)] = 0;
    }
}

// ---------------- bf16 MFMA GEMM:  C[M,N] = A[M,Kp] * B[N,Kp]^T ----------------
// EPI: 0 = f32 store, 3 = relu(x+bias)->bf16 (ld 928), 4 = x+bias->f32,
//      5 = QKV scatter (qwp f32 + qr_bf bf16[64] + Kp/Vp f32),
//      6 = rk -> rk_bf bf16 [n][2112][64],
//      7 = BD batched GEMM -> BD[lb][q][j][NH] bf16 (n innermost!)
template<int EPI>
__global__ __launch_bounds__(256)
void gemm_mfma(const ushortt* __restrict__ A, const ushortt* __restrict__ B,
               const float* __restrict__ bias, void* __restrict__ Cout,
               int M, int N, int Kpp, int ldc,
               const float* __restrict__ bias2, float* __restrict__ out2,
               float* __restrict__ out3, float* __restrict__ out4, int bofs) {
    __shared__ __align__(16) ushortt As[128 * 32];
    __shared__ __align__(16) ushortt Bs[64 * 32];
    const int tid = threadIdx.x;
    const int wid = tid >> 6, lane = tid & 63;
    const int bRow = blockIdx.y * 128, bCol = blockIdx.x * 64;

    int lb = 0, nh7 = 0;
    if (EPI == 7) {                       // batched: z = local_b * NH + n
        const int z = blockIdx.z;
        lb = z / NH; nh7 = z - lb * NH;
        A += (((size_t)(bofs + lb) * NH + nh7) * 1024) * 64;
        B += (size_t)nh7 * RLP * 64;
    }

    float4v acc[2][4];
    const float4v zz = {0.f, 0.f, 0.f, 0.f};
    #pragma unroll
    for (int m = 0; m < 2; ++m)
        #pragma unroll
        for (int n = 0; n < 4; ++n) acc[m][n] = zz;

    const int arow = tid >> 1, acol = (tid & 1) * 16;
    const int brow = tid >> 2, bcol = (tid & 3) * 8;
    const int fr = lane & 15, kg = lane >> 4;

    for (int k0 = 0; k0 < Kpp; k0 += 32) {
        const ushortt* ag = A + (size_t)(bRow + arow) * Kpp + k0 + acol;
        float4v a0 = *(const float4v*)ag;
        float4v a1 = *(const float4v*)(ag + 8);
        const ushortt* bg = B + (size_t)(bCol + brow) * Kpp + k0 + bcol;
        float4v b0 = *(const float4v*)bg;
        __syncthreads();
        *(float4v*)&As[arow * 32 + acol] = a0;
        *(float4v*)&As[arow * 32 + acol + 8] = a1;
        *(float4v*)&Bs[brow * 32 + bcol] = b0;
        __syncthreads();

        short8 bf[4];
        #pragma unroll
        for (int n = 0; n < 4; ++n)
            bf[n] = *(const short8*)&Bs[(n * 16 + fr) * 32 + kg * 8];
        #pragma unroll
        for (int m = 0; m < 2; ++m) {
            short8 af = *(const short8*)&As[(wid * 32 + m * 16 + fr) * 32 + kg * 8];
            #pragma unroll
            for (int n = 0; n < 4; ++n)
                acc[m][n] = __builtin_amdgcn_mfma_f32_16x16x32_bf16(af, bf[n], acc[m][n], 0, 0, 0);
        }
    }

    #pragma unroll
    for (int m = 0; m < 2; ++m)
        #pragma unroll
        for (int n = 0; n < 4; ++n)
            #pragma unroll
            for (int j = 0; j < 4; ++j) {
                const int row = bRow + wid * 32 + m * 16 + (lane >> 4) * 4 + j;
                const int col = bCol + n * 16 + (lane & 15);
                const float v = acc[m][n][j];
                if (EPI == 0) {
                    if (row < M && col < N) ((float*)Cout)[(size_t)row * ldc + col] = v;
                } else if (EPI == 3) {
                    if (row < M && col < 928) {
                        float h = (col < DI) ? fmaxf(v + bias[col], 0.f) : 0.f;
                        ((ushortt*)Cout)[(size_t)row * 928 + col] = f2bf(h);
                    }
                } else if (EPI == 4) {
                    if (row < M && col < N) ((float*)Cout)[(size_t)row * ldc + col] = v + bias[col];
                } else if (EPI == 5) {
                    if (col < H3) {
                        int part = col / 380;
                        int c = col - part * 380;
                        int nh = c / 38, d = c - nh * 38;
                        int q = row >> 2, b2 = row & 3;
                        size_t idx = (((size_t)b2 * NH + nh) * 1024 + q) * 40 + d;
                        if (part == 0) {
                            ((float*)Cout)[idx] = v + bias[c];                 // qwp (+r_w_bias)
                            ((ushortt*)out2)[(((size_t)b2 * NH + nh) * 1024 + q) * 64 + d]
                                = f2bf(v + bias2[c]);                          // qr_bf (+r_r_bias)
                        } else if (part == 1) out3[idx] = v;                   // Kp
                        else out4[idx] = v;                                    // Vp
                    }
                } else if (EPI == 6) {
                    if (row < RLEN && col < DM) {
                        int nh = col / 38, d = col - nh * 38;
                        ((ushortt*)Cout)[((size_t)nh * RLP + row) * 64 + d] = f2bf(v);
                    }
                } else {  // EPI 7: BD store, n innermost
                    if (col < RLEN)
                        ((ushortt*)Cout)[(((size_t)lb * 1024 + row) * RLEN + col) * NH + nh7] = f2bf(v);
                }
            }
}

// ---------------- split-K fused attention, 32 q-rows per block ----------------
// qwp/Kp/Vp: f32 [b][n][1024][40]; BD: bf16 [lb][1024 q][2049 j][NH]
// grid: x = n (heads fastest -> co-resident, share BD lines + relpos), y = qc, z = b*KS+s
__global__ __launch_bounds__(256)
void attn4(const float* __restrict__ qwp, const float* __restrict__ Kp,
           const float* __restrict__ Vp, const ushortt* __restrict__ BD,
           const int* __restrict__ relpos,
           float* __restrict__ op, float2* __restrict__ ml, int b0) {
    const int n = blockIdx.x;
    const int qc = 31 - blockIdx.y;              // heavy chunks dispatch first
    const int qbase = qc * 32;
    const int lbd = blockIdx.z / KS;             // local b (BD index)
    const int s = blockIdx.z - lbd * KS;
    const int b = b0 + lbd;
    const int tid = threadIdx.x;
    const int row = tid >> 3, kg = tid & 7;
    const int qi = qbase + row;
    const size_t bn = (size_t)b * NH + n;
    const size_t prow = ((size_t)s * (BSZ * NH) + bn) * 1024 + qi;

    const int ntchunk = (qbase + 95) >> 6;       // ceil((qbase+32)/64)
    const int tbeg = s * 8;                      // KS=2: 8 tiles (=512 k) per split
    const int tend = min(tbeg + 8, ntchunk);
    if (tbeg >= tend) {                          // inactive split
        if (kg == 0) ml[prow] = make_float2(-INFINITY, 0.f);
        return;
    }

    __shared__ __align__(16) float KtL[64 * 40];
    __shared__ __align__(16) float VtL[64 * 40];
    __shared__ float pL[32 * 66];

    const float* Kbase = Kp + bn * 1024 * 40;
    const float* Vbase = Vp + bn * 1024 * 40;

    // preload own qw row into registers
    float4v qw[10];
    {
        const float4v* src = (const float4v*)(qwp + (bn * 1024 + qi) * 40);
        #pragma unroll
        for (int i = 0; i < 10; ++i) qw[i] = src[i];
    }
    float o[5] = {0.f, 0.f, 0.f, 0.f, 0.f};
    float mrun = -INFINITY, lrun = 0.f;
    const int* rp = relpos + ((size_t)b * QLEN + qi) * QLEN;
    const ushortt* bdrow = BD + (((size_t)lbd * 1024 + qi) * RLEN) * NH + n;

    for (int kt = tbeg; kt < tend; ++kt) {
        const int k0 = kt * 64;
        __syncthreads();
        {
            const float4v* ks = (const float4v*)(Kbase + (size_t)k0 * 40);
            const float4v* vs = (const float4v*)(Vbase + (size_t)k0 * 40);
            for (int e = tid; e < 640; e += 256) {
                ((float4v*)KtL)[e] = ks[e];
                ((float4v*)VtL)[e] = vs[e];
            }
        }
        __syncthreads();

        // prefetch relpos -> j indices, then BD values (breaks the serial chain)
        int jv[8];
        #pragma unroll
        for (int ss = 0; ss < 8; ++ss) {
            const int kk = k0 + kg + ss * 8;
            int j = -1;
            if (kk <= qi) {
                int rpv = rp[kk];
                rpv = rpv < -1024 ? -1024 : (rpv > 1024 ? 1024 : rpv);
                j = 1024 - rpv;
            }
            jv[ss] = j;
        }
        float bdv[8];
        #pragma unroll
        for (int ss = 0; ss < 8; ++ss)
            bdv[ss] = (jv[ss] >= 0) ? bf2f(bdrow[(size_t)jv[ss] * NH]) : 0.f;

        float sarr[8];
        float pmax = -INFINITY;
        #pragma unroll
        for (int ss = 0; ss < 8; ++ss) {
            float sv = -INFINITY;
            if (jv[ss] >= 0) {
                const int k = kg + ss * 8;
                float acc1 = 0.f;
                const float4v* kt4 = (const float4v*)(KtL + k * 40);
                #pragma unroll
                for (int i = 0; i < 10; ++i) {
                    float4v kv = kt4[i];
                    acc1 += qw[i][0] * kv[0] + qw[i][1] * kv[1]
                          + qw[i][2] * kv[2] + qw[i][3] * kv[3];
                }
                sv = (acc1 + bdv[ss]) * SCALE;
            }
            sarr[ss] = sv;
            pmax = fmaxf(pmax, sv);
        }
        pmax = fmaxf(pmax, __shfl_xor(pmax, 1, 64));
        pmax = fmaxf(pmax, __shfl_xor(pmax, 2, 64));
        pmax = fmaxf(pmax, __shfl_xor(pmax, 4, 64));
        const float nm = fmaxf(mrun, pmax);
        const float corr = __expf(mrun - nm);   // first tile: exp(-inf)=0
        float psum = 0.f;
        float* prw = pL + row * 66;
        #pragma unroll
        for (int ss = 0; ss < 8; ++ss) {
            float p = __expf(sarr[ss] - nm);
            psum += p;
            prw[kg + ss * 8] = p;
        }
        psum += __shfl_xor(psum, 1, 64);
        psum += __shfl_xor(psum, 2, 64);
        psum += __shfl_xor(psum, 4, 64);
        lrun = lrun * corr + psum;
        mrun = nm;
        #pragma unroll
        for (int jj = 0; jj < 5; ++jj) o[jj] *= corr;
        int kmax = qi - k0 + 1; if (kmax > 64) kmax = 64;
        #pragma unroll 4
        for (int k = 0; k < kmax; ++k) {
            float p = prw[k];
            const float* vr = VtL + k * 40;
            float4v v4 = *(const float4v*)(vr + 4 * kg);
            float v1 = vr[32 + kg];
            o[0] += p * v4[0]; o[1] += p * v4[1];
            o[2] += p * v4[2]; o[3] += p * v4[3];
            o[4] += p * v1;
        }
    }
    float* oprow = op + prow * 40;
    #pragma unroll
    for (int jj = 0; jj < 4; ++jj) oprow[4 * kg + jj] = o[jj];
    oprow[32 + kg] = o[4];
    if (kg == 0) ml[prow] = make_float2(mrun, lrun);
}

// ---------------- combine split-K partials -> vec (bf16) ----------------
__global__ __launch_bounds__(256)
void attn_combine(const float* __restrict__ op, const float2* __restrict__ ml,
                  ushortt* __restrict__ vec) {
    const int idx = blockIdx.x * 256 + threadIdx.x;
    if (idx >= BSZ * NH * 1024 * 38) return;
    const int d = idx % 38;
    const int rh = idx / 38;                 // bn*1024 + q
    const int q = rh & 1023;
    const int bn = rh >> 10;
    const int b = bn / NH, n = bn - b * NH;
    const float2 a = ml[rh];
    const float2 c = ml[(size_t)BSZ * NH * 1024 + rh];
    const float M = fmaxf(a.x, c.x);
    float l = 0.f, o = 0.f;
    if (a.y > 0.f) {
        float w = __expf(a.x - M);
        l += a.y * w;
        o += op[(size_t)rh * 40 + d] * w;
    }
    if (c.y > 0.f) {
        float w = __expf(c.x - M);
        l += c.y * w;
        o += op[((size_t)BSZ * NH * 1024 + rh) * 40 + d] * w;
    }
    vec[((size_t)q * BSZ + b) * 384 + (size_t)n * 38 + d] = f2bf(o / l);
}

// ---------------- residual + LayerNorm ----------------
template<bool WRITE_BF>
__global__ __launch_bounds__(256)
void ln_kernel(const float* __restrict__ x1, const float* __restrict__ x2,
               const float* __restrict__ g, const float* __restrict__ bb,
               float* __restrict__ outf, ushortt* __restrict__ outbf) {
    const int row = blockIdx.x;
    const float* p1 = x1 + (size_t)row * DM;
    const float* p2 = x2 + (size_t)row * DM;
    __shared__ float xb[DM];
    __shared__ float red[256];
    const int tid = threadIdx.x;
    float s = 0.f;
    for (int i = tid; i < DM; i += 256) { float v = p1[i] + p2[i]; xb[i] = v; s += v; }
    red[tid] = s; __syncthreads();
    for (int st = 128; st > 0; st >>= 1) { if (tid < st) red[tid] += red[tid + st]; __syncthreads(); }
    const float mean = red[0] / DM;
    __syncthreads();
    float s2 = 0.f;
    for (int i = tid; i < DM; i += 256) { float d = xb[i] - mean; s2 += d * d; }
    red[tid] = s2; __syncthreads();
    for (int st = 128; st > 0; st >>= 1) { if (tid < st) red[tid] += red[tid + st]; __syncthreads(); }
    const float rstd = rsqrtf(red[0] / DM + 1e-5f);
    for (int i = tid; i < (WRITE_BF ? 384 : DM); i += 256) {
        float v = 0.f;
        if (i < DM) {
            v = (xb[i] - mean) * rstd * g[i] + bb[i];
            outf[(size_t)row * DM + i] = v;
        }
        if (WRITE_BF) outbf[(size_t)row * 384 + i] = f2bf(i < DM ? v : 0.f);
    }
}

extern "C" void kernel_launch(void* const* d_in, const int* in_sizes, int n_in,
                              void* d_out, int out_size, void* d_ws, size_t ws_size,
                              hipStream_t stream) {
    const float* w     = (const float*)d_in[0];
    const float* r     = (const float*)d_in[1];
    const float* rwb   = (const float*)d_in[2];
    const float* rrb   = (const float*)d_in[3];
    const float* qkv_w = (const float*)d_in[4];
    const float* r_w   = (const float*)d_in[5];
    const float* o_w   = (const float*)d_in[6];
    const float* ln1g  = (const float*)d_in[7];
    const float* ln1b  = (const float*)d_in[8];
    const float* ffw1  = (const float*)d_in[9];
    const float* ffb1  = (const float*)d_in[10];
    const float* ffw2  = (const float*)d_in[11];
    const float* ffb2  = (const float*)d_in[12];
    const float* ln2g  = (const float*)d_in[13];
    const float* ln2b  = (const float*)d_in[14];
    const int*   relpos = (const int*)d_in[16];
    float* out = (float*)d_out;

    char* cur = (char*)d_ws;
    auto alloc = [&](size_t bytes) { char* p = cur; cur += (bytes + 255) & ~(size_t)255; return p; };
    ushortt* w_bf    = (ushortt*)alloc((size_t)4096 * 384 * 2);
    ushortt* qkv_bf  = (ushortt*)alloc((size_t)1152 * 384 * 2);
    ushortt* r_bf    = (ushortt*)alloc((size_t)2176 * 384 * 2);
    ushortt* rw_bf   = (ushortt*)alloc((size_t)384 * 384 * 2);
    ushortt* ow_bf   = (ushortt*)alloc((size_t)384 * 384 * 2);
    ushortt* f1_bf   = (ushortt*)alloc((size_t)960 * 384 * 2);
    ushortt* f2_bf   = (ushortt*)alloc((size_t)384 * 928 * 2);
    float*   qwp     = (float*)alloc((size_t)BSZ * NH * 1024 * 40 * 4);
    float*   Kpp     = (float*)alloc((size_t)BSZ * NH * 1024 * 40 * 4);
    float*   Vpp     = (float*)alloc((size_t)BSZ * NH * 1024 * 40 * 4);
    ushortt* qr_bf   = (ushortt*)alloc((size_t)BSZ * NH * 1024 * 64 * 2);
    ushortt* rk_bf   = (ushortt*)alloc((size_t)NH * RLP * 64 * 2);
    ushortt* vec_bf  = (ushortt*)alloc((size_t)4096 * 384 * 2);
    ushortt* out1_bf = (ushortt*)alloc((size_t)4096 * 384 * 2);
    ushortt* h1_bf   = (ushortt*)alloc((size_t)4096 * 928 * 2);
    float*   attnf   = (float*)alloc((size_t)4096 * DM * 4);
    float*   out1f   = (float*)alloc((size_t)4096 * DM * 4);
    float*   core    = (float*)alloc((size_t)4096 * DM * 4);

    // split-K partials alias attnf/out1f/core (dead until after combine)
    float*  op_part = attnf;
    float2* ml_part = (float2*)(attnf + (size_t)KS * BSZ * NH * 1024 * 40);

    // BD buffer: bf16 [lb][1024 q][2049 j][NH]
    const size_t bd_b_bytes = (size_t)1024 * RLEN * NH * 2;   // per-b: ~41 MB
    ushortt* BD = (ushortt*)alloc(bd_b_bytes * BSZ);
    bool full = ((size_t)(cur - (char*)d_ws) <= ws_size);
    if (!full) { cur = (char*)BD; BD = (ushortt*)alloc(bd_b_bytes); }  // per-b reuse

    auto cgrid = [](size_t total) { return dim3((unsigned)((total + 255) / 256)); };
    hipMemsetAsync(qr_bf, 0, (size_t)BSZ * NH * 1024 * 64 * 2, stream);
    hipMemsetAsync(rk_bf, 0, (size_t)NH * RLP * 64 * 2, stream);
    convpad<<<cgrid((size_t)4096 * 384), 256, 0, stream>>>(w, w_bf, 4096, DM, 4096, 384);
    convpad<<<cgrid((size_t)1152 * 384), 256, 0, stream>>>(qkv_w, qkv_bf, H3, DM, 1152, 384);
    convpad<<<cgrid((size_t)2176 * 384), 256, 0, stream>>>(r, r_bf, RLEN, DM, 2176, 384);
    convpad<<<cgrid((size_t)384 * 384), 256, 0, stream>>>(r_w, rw_bf, DM, DM, 384, 384);
    convpad<<<cgrid((size_t)384 * 384), 256, 0, stream>>>(o_w, ow_bf, DM, DM, 384, 384);
    convpad<<<cgrid((size_t)960 * 384), 256, 0, stream>>>(ffw1, f1_bf, DI, DM, 960, 384);
    convpad<<<cgrid((size_t)384 * 928), 256, 0, stream>>>(ffw2, f2_bf, DM, DI, 384, 928);
    init_pads<<<cgrid((size_t)BSZ * NH * 1024 * 2), 256, 0, stream>>>(qwp, Kpp, Vpp, vec_bf);

    // QKV GEMM with scatter epilogue -> qwp / qr_bf / Kpp / Vpp
    gemm_mfma<5><<<dim3(18, 32), 256, 0, stream>>>(w_bf, qkv_bf, rwb, qwp, 4096, H3, 384, 0,
                                                   rrb, (float*)qr_bf, Kpp, Vpp, 0);
    // rk GEMM -> rk_bf  bf16 [n][2112][64]
    gemm_mfma<6><<<dim3(6, 17), 256, 0, stream>>>(r_bf, rw_bf, nullptr, rk_bf, RLEN, DM, 384, 0,
                                                  nullptr, nullptr, nullptr, nullptr, 0);
    if (full) {
        // BDfull = qr @ rk^T, batched over all (b,n), n-innermost store
        gemm_mfma<7><<<dim3(33, 8, BSZ * NH), 256, 0, stream>>>(
            qr_bf, rk_bf, nullptr, BD, 1024, RLEN, 64, 0,
            nullptr, nullptr, nullptr, nullptr, 0);
        attn4<<<dim3(NH, 32, BSZ * KS), 256, 0, stream>>>(qwp, Kpp, Vpp, BD, relpos,
                                                          op_part, ml_part, 0);
    } else {
        for (int b = 0; b < BSZ; ++b) {
            gemm_mfma<7><<<dim3(33, 8, NH), 256, 0, stream>>>(
                qr_bf, rk_bf, nullptr, BD, 1024, RLEN, 64, 0,
                nullptr, nullptr, nullptr, nullptr, b);
            attn4<<<dim3(NH, 32, KS), 256, 0, stream>>>(qwp, Kpp, Vpp, BD, relpos,
                                                        op_part, ml_part, b);
        }
    }
    attn_combine<<<cgrid((size_t)BSZ * NH * 1024 * 38), 256, 0, stream>>>(op_part, ml_part, vec_bf);
    // attn_out = vec @ o_w^T   (overwrites op_part alias -- partials are dead)
    gemm_mfma<0><<<dim3(6, 32), 256, 0, stream>>>(vec_bf, ow_bf, nullptr, attnf, 4096, DM, 384, DM,
                                                  nullptr, nullptr, nullptr, nullptr, 0);
    ln_kernel<true><<<4096, 256, 0, stream>>>(w, attnf, ln1g, ln1b, out1f, out1_bf);
    gemm_mfma<3><<<dim3(15, 32), 256, 0, stream>>>(out1_bf, f1_bf, ffb1, h1_bf, 4096, DI, 384, 928,
                                                   nullptr, nullptr, nullptr, nullptr, 0);
    gemm_mfma<4><<<dim3(6, 32), 256, 0, stream>>>(h1_bf, f2_bf, ffb2, core, 4096, DM, 928, DM,
                                                  nullptr, nullptr, nullptr, nullptr, 0);
    ln_kernel<false><<<4096, 256, 0, stream>>>(out1f, core, ln2g, ln2b, out, nullptr);
}

// Round 10
// 445.029 us; speedup vs baseline: 1.9233x; 1.9233x over previous
//
#include <hip/hip_runtime.h>
#include <math.h>

#define QLEN 1024
#define BSZ 4
#define NH 10
#define DH 38
#define DM 380
#define DI 900
#define H3 1140
#define RLEN 2049
#define RLP 2112                      // RLEN padded to 33*64
#define SCALE 0.16222142113076254f   // 1/sqrt(38)
#define KS 2                          // k-splits in attention

typedef unsigned short ushortt;
typedef __attribute__((ext_vector_type(8))) short short8;
typedef __attribute__((ext_vector_type(4))) float float4v;

__device__ __forceinline__ float bf2f(ushortt u) {
    return __uint_as_float(((unsigned int)u) << 16);
}
__device__ __forceinline__ ushortt f2bf(float f) {
    unsigned int u = __float_as_uint(f);
    u += 0x7fffu + ((u >> 16) & 1u);   // RNE
    return (ushortt)(u >> 16);
}

// ---------- f32 [R][C] -> bf16 [Rp][Cp], zero-padded ----------
__global__ __launch_bounds__(256)
void convpad(const float* __restrict__ src, ushortt* __restrict__ dst,
             int R, int C, int Rp, int Cp) {
    const int total = Rp * Cp;
    for (int i = blockIdx.x * 256 + threadIdx.x; i < total; i += gridDim.x * 256) {
        int r = i / Cp, c = i - r * Cp;
        float v = (r < R && c < C) ? src[(size_t)r * C + c] : 0.f;
        dst[i] = f2bf(v);
    }
}

// ---------- zero the pad lanes once per launch ----------
__global__ __launch_bounds__(256)
void init_pads(float* __restrict__ qwp, float* __restrict__ Kp, float* __restrict__ Vp,
               ushortt* __restrict__ vec) {
    const int i = blockIdx.x * 256 + threadIdx.x;
    if (i < BSZ * NH * 1024 * 2) {                       // d=38,39 of the head arrays
        size_t idx = (size_t)(i >> 1) * 40 + 38 + (i & 1);
        qwp[idx] = 0.f; Kp[idx] = 0.f; Vp[idx] = 0.f;
    }
    if (i < 4096 * 4) {                                  // vec cols 380..383
        vec[(size_t)(i >> 2) * 384 + 380 + (i & 3)] = 0;
    }
}

// ---------------- bf16 MFMA GEMM:  C[M,N] = A[M,Kp] * B[N,Kp]^T ----------------
// EPI: 0 = f32 store, 3 = relu(x+bias)->bf16 (ld 928), 4 = x+bias->f32,
//      5 = QKV scatter (qwp f32 + qr_bf bf16[64] + Kp/Vp f32),
//      6 = rk -> rk_bf bf16 [n][2112][64],
//      7 = BD batched GEMM -> BD[lb][q][j][NH] bf16, 1-D XCD-grouped grid:
//          the 10 head-blocks of each (b,qt,jt) land on ONE XCD so their
//          interleaved 2B stores merge in that XCD's L2.
template<int EPI>
__global__ __launch_bounds__(256)
void gemm_mfma(const ushortt* __restrict__ A, const ushortt* __restrict__ B,
               const float* __restrict__ bias, void* __restrict__ Cout,
               int M, int N, int Kpp, int ldc,
               const float* __restrict__ bias2, float* __restrict__ out2,
               float* __restrict__ out3, float* __restrict__ out4, int bofs) {
    __shared__ __align__(16) ushortt As[128 * 32];
    __shared__ __align__(16) ushortt Bs[64 * 32];
    const int tid = threadIdx.x;
    const int wid = tid >> 6, lane = tid & 63;

    int bRow, bCol, lb = 0, nh7 = 0;
    if (EPI == 7) {
        const int bid = blockIdx.x;
        const int xcd = bid & 7, t = bid >> 3;
        const int gl = t / NH, member = t - gl * NH;   // member = head n
        const int G = gl * 8 + xcd;                    // group = bq*33 + jt
        const int bq = G / 33, jt = G - bq * 33;       // bq = lb*8 + qt
        lb = bq >> 3;
        const int qt = bq & 7;
        nh7 = member;
        bRow = qt * 128; bCol = jt * 64;
        A += (((size_t)(bofs + lb) * NH + nh7) * 1024) * 64;
        B += (size_t)nh7 * RLP * 64;
    } else {
        bRow = blockIdx.y * 128; bCol = blockIdx.x * 64;
    }

    float4v acc[2][4];
    const float4v zz = {0.f, 0.f, 0.f, 0.f};
    #pragma unroll
    for (int m = 0; m < 2; ++m)
        #pragma unroll
        for (int n = 0; n < 4; ++n) acc[m][n] = zz;

    const int arow = tid >> 1, acol = (tid & 1) * 16;
    const int brow = tid >> 2, bcol = (tid & 3) * 8;
    const int fr = lane & 15, kg = lane >> 4;

    for (int k0 = 0; k0 < Kpp; k0 += 32) {
        const ushortt* ag = A + (size_t)(bRow + arow) * Kpp + k0 + acol;
        float4v a0 = *(const float4v*)ag;
        float4v a1 = *(const float4v*)(ag + 8);
        const ushortt* bg = B + (size_t)(bCol + brow) * Kpp + k0 + bcol;
        float4v b0 = *(const float4v*)bg;
        __syncthreads();
        *(float4v*)&As[arow * 32 + acol] = a0;
        *(float4v*)&As[arow * 32 + acol + 8] = a1;
        *(float4v*)&Bs[brow * 32 + bcol] = b0;
        __syncthreads();

        short8 bf[4];
        #pragma unroll
        for (int n = 0; n < 4; ++n)
            bf[n] = *(const short8*)&Bs[(n * 16 + fr) * 32 + kg * 8];
        #pragma unroll
        for (int m = 0; m < 2; ++m) {
            short8 af = *(const short8*)&As[(wid * 32 + m * 16 + fr) * 32 + kg * 8];
            #pragma unroll
            for (int n = 0; n < 4; ++n)
                acc[m][n] = __builtin_amdgcn_mfma_f32_16x16x32_bf16(af, bf[n], acc[m][n], 0, 0, 0);
        }
    }

    #pragma unroll
    for (int m = 0; m < 2; ++m)
        #pragma unroll
        for (int n = 0; n < 4; ++n)
            #pragma unroll
            for (int j = 0; j < 4; ++j) {
                const int row = bRow + wid * 32 + m * 16 + (lane >> 4) * 4 + j;
                const int col = bCol + n * 16 + (lane & 15);
                const float v = acc[m][n][j];
                if (EPI == 0) {
                    if (row < M && col < N) ((float*)Cout)[(size_t)row * ldc + col] = v;
                } else if (EPI == 3) {
                    if (row < M && col < 928) {
                        float h = (col < DI) ? fmaxf(v + bias[col], 0.f) : 0.f;
                        ((ushortt*)Cout)[(size_t)row * 928 + col] = f2bf(h);
                    }
                } else if (EPI == 4) {
                    if (row < M && col < N) ((float*)Cout)[(size_t)row * ldc + col] = v + bias[col];
                } else if (EPI == 5) {
                    if (col < H3) {
                        int part = col / 380;
                        int c = col - part * 380;
                        int nh = c / 38, d = c - nh * 38;
                        int q = row >> 2, b2 = row & 3;
                        size_t idx = (((size_t)b2 * NH + nh) * 1024 + q) * 40 + d;
                        if (part == 0) {
                            ((float*)Cout)[idx] = v + bias[c];                 // qwp (+r_w_bias)
                            ((ushortt*)out2)[(((size_t)b2 * NH + nh) * 1024 + q) * 64 + d]
                                = f2bf(v + bias2[c]);                          // qr_bf (+r_r_bias)
                        } else if (part == 1) out3[idx] = v;                   // Kp
                        else out4[idx] = v;                                    // Vp
                    }
                } else if (EPI == 6) {
                    if (row < RLEN && col < DM) {
                        int nh = col / 38, d = col - nh * 38;
                        ((ushortt*)Cout)[((size_t)nh * RLP + row) * 64 + d] = f2bf(v);
                    }
                } else {  // EPI 7: BD store, n innermost
                    if (col < RLEN)
                        ((ushortt*)Cout)[(((size_t)lb * 1024 + row) * RLEN + col) * NH + nh7] = f2bf(v);
                }
            }
}

// ---------------- split-K fused attention, 32 q-rows per block ----------------
// qwp/Kp/Vp: f32 [b][n][1024][40]; BD: bf16 [lb][1024 q][2049 j][NH]
// 1-D XCD-grouped grid: the 20 (n,s) blocks of each (qc,b) land on ONE XCD so
// they share BD lines + relpos rows in that XCD's L2. Heavy qc dispatch first.
__global__ __launch_bounds__(256)
void attn4(const float* __restrict__ qwp, const float* __restrict__ Kp,
           const float* __restrict__ Vp, const ushortt* __restrict__ BD,
           const int* __restrict__ relpos,
           float* __restrict__ op, float2* __restrict__ ml, int b0, int nb) {
    const int bid = blockIdx.x;
    const int xcd = bid & 7, t = bid >> 3;
    const int gl = t / 20, member = t - gl * 20;   // member: n + 10*s
    const int G = gl * 8 + xcd;                    // group = (31-qc)*nb + lbd
    const int qc = 31 - G / nb;
    const int lbd = G - (31 - qc) * nb;
    const int n = member % NH, s = member / NH;
    const int qbase = qc * 32;
    const int b = b0 + lbd;
    const int tid = threadIdx.x;
    const int row = tid >> 3, kg = tid & 7;
    const int qi = qbase + row;
    const size_t bn = (size_t)b * NH + n;
    const size_t prow = ((size_t)s * (BSZ * NH) + bn) * 1024 + qi;

    const int ntchunk = (qbase + 95) >> 6;       // ceil((qbase+32)/64)
    const int tbeg = s * 8;                      // KS=2: 8 tiles (=512 k) per split
    const int tend = min(tbeg + 8, ntchunk);
    if (tbeg >= tend) {                          // inactive split
        if (kg == 0) ml[prow] = make_float2(-INFINITY, 0.f);
        return;
    }

    __shared__ __align__(16) float KtL[64 * 40];
    __shared__ __align__(16) float VtL[64 * 40];
    __shared__ float pL[32 * 66];

    const float* Kbase = Kp + bn * 1024 * 40;
    const float* Vbase = Vp + bn * 1024 * 40;

    // preload own qw row into registers
    float4v qw[10];
    {
        const float4v* src = (const float4v*)(qwp + (bn * 1024 + qi) * 40);
        #pragma unroll
        for (int i = 0; i < 10; ++i) qw[i] = src[i];
    }
    float o[5] = {0.f, 0.f, 0.f, 0.f, 0.f};
    float mrun = -INFINITY, lrun = 0.f;
    const int* rp = relpos + ((size_t)b * QLEN + qi) * QLEN;
    const ushortt* bdrow = BD + (((size_t)lbd * 1024 + qi) * RLEN) * NH + n;

    for (int kt = tbeg; kt < tend; ++kt) {
        const int k0 = kt * 64;
        __syncthreads();
        {
            const float4v* ks = (const float4v*)(Kbase + (size_t)k0 * 40);
            const float4v* vs = (const float4v*)(Vbase + (size_t)k0 * 40);
            for (int e = tid; e < 640; e += 256) {
                ((float4v*)KtL)[e] = ks[e];
                ((float4v*)VtL)[e] = vs[e];
            }
        }
        __syncthreads();

        // prefetch relpos -> j indices, then BD values (breaks the serial chain)
        int jv[8];
        #pragma unroll
        for (int ss = 0; ss < 8; ++ss) {
            const int kk = k0 + kg + ss * 8;
            int j = -1;
            if (kk <= qi) {
                int rpv = rp[kk];
                rpv = rpv < -1024 ? -1024 : (rpv > 1024 ? 1024 : rpv);
                j = 1024 - rpv;
            }
            jv[ss] = j;
        }
        float bdv[8];
        #pragma unroll
        for (int ss = 0; ss < 8; ++ss)
            bdv[ss] = (jv[ss] >= 0) ? bf2f(bdrow[(size_t)jv[ss] * NH]) : 0.f;

        float sarr[8];
        float pmax = -INFINITY;
        #pragma unroll
        for (int ss = 0; ss < 8; ++ss) {
            float sv = -INFINITY;
            if (jv[ss] >= 0) {
                const int k = kg + ss * 8;
                float acc1 = 0.f;
                const float4v* kt4 = (const float4v*)(KtL + k * 40);
                #pragma unroll
                for (int i = 0; i < 10; ++i) {
                    float4v kv = kt4[i];
                    acc1 += qw[i][0] * kv[0] + qw[i][1] * kv[1]
                          + qw[i][2] * kv[2] + qw[i][3] * kv[3];
                }
                sv = (acc1 + bdv[ss]) * SCALE;
            }
            sarr[ss] = sv;
            pmax = fmaxf(pmax, sv);
        }
        pmax = fmaxf(pmax, __shfl_xor(pmax, 1, 64));
        pmax = fmaxf(pmax, __shfl_xor(pmax, 2, 64));
        pmax = fmaxf(pmax, __shfl_xor(pmax, 4, 64));
        const float nm = fmaxf(mrun, pmax);
        const float corr = __expf(mrun - nm);   // first tile: exp(-inf)=0
        float psum = 0.f;
        float* prw = pL + row * 66;
        #pragma unroll
        for (int ss = 0; ss < 8; ++ss) {
            float p = __expf(sarr[ss] - nm);
            psum += p;
            prw[kg + ss * 8] = p;
        }
        psum += __shfl_xor(psum, 1, 64);
        psum += __shfl_xor(psum, 2, 64);
        psum += __shfl_xor(psum, 4, 64);
        lrun = lrun * corr + psum;
        mrun = nm;
        #pragma unroll
        for (int jj = 0; jj < 5; ++jj) o[jj] *= corr;
        int kmax = qi - k0 + 1; if (kmax > 64) kmax = 64;
        #pragma unroll 4
        for (int k = 0; k < kmax; ++k) {
            float p = prw[k];
            const float* vr = VtL + k * 40;
            float4v v4 = *(const float4v*)(vr + 4 * kg);
            float v1 = vr[32 + kg];
            o[0] += p * v4[0]; o[1] += p * v4[1];
            o[2] += p * v4[2]; o[3] += p * v4[3];
            o[4] += p * v1;
        }
    }
    float* oprow = op + prow * 40;
    #pragma unroll
    for (int jj = 0; jj < 4; ++jj) oprow[4 * kg + jj] = o[jj];
    oprow[32 + kg] = o[4];
    if (kg == 0) ml[prow] = make_float2(mrun, lrun);
}

// ---------------- combine split-K partials -> vec (bf16) ----------------
__global__ __launch_bounds__(256)
void attn_combine(const float* __restrict__ op, const float2* __restrict__ ml,
                  ushortt* __restrict__ vec) {
    const int idx = blockIdx.x * 256 + threadIdx.x;
    if (idx >= BSZ * NH * 1024 * 38) return;
    const int d = idx % 38;
    const int rh = idx / 38;                 // bn*1024 + q
    const int q = rh & 1023;
    const int bn = rh >> 10;
    const int b = bn / NH, n = bn - b * NH;
    const float2 a = ml[rh];
    const float2 c = ml[(size_t)BSZ * NH * 1024 + rh];
    const float M = fmaxf(a.x, c.x);
    float l = 0.f, o = 0.f;
    if (a.y > 0.f) {
        float w = __expf(a.x - M);
        l += a.y * w;
        o += op[(size_t)rh * 40 + d] * w;
    }
    if (c.y > 0.f) {
        float w = __expf(c.x - M);
        l += c.y * w;
        o += op[((size_t)BSZ * NH * 1024 + rh) * 40 + d] * w;
    }
    vec[((size_t)q * BSZ + b) * 384 + (size_t)n * 38 + d] = f2bf(o / l);
}

// ---------------- residual + LayerNorm ----------------
template<bool WRITE_BF>
__global__ __launch_bounds__(256)
void ln_kernel(const float* __restrict__ x1, const float* __restrict__ x2,
               const float* __restrict__ g, const float* __restrict__ bb,
               float* __restrict__ outf, ushortt* __restrict__ outbf) {
    const int row = blockIdx.x;
    const float* p1 = x1 + (size_t)row * DM;
    const float* p2 = x2 + (size_t)row * DM;
    __shared__ float xb[DM];
    __shared__ float red[256];
    const int tid = threadIdx.x;
    float s = 0.f;
    for (int i = tid; i < DM; i += 256) { float v = p1[i] + p2[i]; xb[i] = v; s += v; }
    red[tid] = s; __syncthreads();
    for (int st = 128; st > 0; st >>= 1) { if (tid < st) red[tid] += red[tid + st]; __syncthreads(); }
    const float mean = red[0] / DM;
    __syncthreads();
    float s2 = 0.f;
    for (int i = tid; i < DM; i += 256) { float d = xb[i] - mean; s2 += d * d; }
    red[tid] = s2; __syncthreads();
    for (int st = 128; st > 0; st >>= 1) { if (tid < st) red[tid] += red[tid + st]; __syncthreads(); }
    const float rstd = rsqrtf(red[0] / DM + 1e-5f);
    for (int i = tid; i < (WRITE_BF ? 384 : DM); i += 256) {
        float v = 0.f;
        if (i < DM) {
            v = (xb[i] - mean) * rstd * g[i] + bb[i];
            outf[(size_t)row * DM + i] = v;
        }
        if (WRITE_BF) outbf[(size_t)row * 384 + i] = f2bf(i < DM ? v : 0.f);
    }
}

extern "C" void kernel_launch(void* const* d_in, const int* in_sizes, int n_in,
                              void* d_out, int out_size, void* d_ws, size_t ws_size,
                              hipStream_t stream) {
    const float* w     = (const float*)d_in[0];
    const float* r     = (const float*)d_in[1];
    const float* rwb   = (const float*)d_in[2];
    const float* rrb   = (const float*)d_in[3];
    const float* qkv_w = (const float*)d_in[4];
    const float* r_w   = (const float*)d_in[5];
    const float* o_w   = (const float*)d_in[6];
    const float* ln1g  = (const float*)d_in[7];
    const float* ln1b  = (const float*)d_in[8];
    const float* ffw1  = (const float*)d_in[9];
    const float* ffb1  = (const float*)d_in[10];
    const float* ffw2  = (const float*)d_in[11];
    const float* ffb2  = (const float*)d_in[12];
    const float* ln2g  = (const float*)d_in[13];
    const float* ln2b  = (const float*)d_in[14];
    const int*   relpos = (const int*)d_in[16];
    float* out = (float*)d_out;

    char* cur = (char*)d_ws;
    auto alloc = [&](size_t bytes) { char* p = cur; cur += (bytes + 255) & ~(size_t)255; return p; };
    ushortt* w_bf    = (ushortt*)alloc((size_t)4096 * 384 * 2);
    ushortt* qkv_bf  = (ushortt*)alloc((size_t)1152 * 384 * 2);
    ushortt* r_bf    = (ushortt*)alloc((size_t)2176 * 384 * 2);
    ushortt* rw_bf   = (ushortt*)alloc((size_t)384 * 384 * 2);
    ushortt* ow_bf   = (ushortt*)alloc((size_t)384 * 384 * 2);
    ushortt* f1_bf   = (ushortt*)alloc((size_t)960 * 384 * 2);
    ushortt* f2_bf   = (ushortt*)alloc((size_t)384 * 928 * 2);
    float*   qwp     = (float*)alloc((size_t)BSZ * NH * 1024 * 40 * 4);
    float*   Kpp     = (float*)alloc((size_t)BSZ * NH * 1024 * 40 * 4);
    float*   Vpp     = (float*)alloc((size_t)BSZ * NH * 1024 * 40 * 4);
    ushortt* qr_bf   = (ushortt*)alloc((size_t)BSZ * NH * 1024 * 64 * 2);
    ushortt* rk_bf   = (ushortt*)alloc((size_t)NH * RLP * 64 * 2);
    ushortt* vec_bf  = (ushortt*)alloc((size_t)4096 * 384 * 2);
    ushortt* out1_bf = (ushortt*)alloc((size_t)4096 * 384 * 2);
    ushortt* h1_bf   = (ushortt*)alloc((size_t)4096 * 928 * 2);
    float*   attnf   = (float*)alloc((size_t)4096 * DM * 4);
    float*   out1f   = (float*)alloc((size_t)4096 * DM * 4);
    float*   core    = (float*)alloc((size_t)4096 * DM * 4);

    // split-K partials alias attnf/out1f/core (dead until after combine)
    float*  op_part = attnf;
    float2* ml_part = (float2*)(attnf + (size_t)KS * BSZ * NH * 1024 * 40);

    // BD buffer: bf16 [lb][1024 q][2049 j][NH]
    const size_t bd_b_bytes = (size_t)1024 * RLEN * NH * 2;   // per-b: ~41 MB
    ushortt* BD = (ushortt*)alloc(bd_b_bytes * BSZ);
    bool full = ((size_t)(cur - (char*)d_ws) <= ws_size);
    if (!full) { cur = (char*)BD; BD = (ushortt*)alloc(bd_b_bytes); }  // per-b reuse

    auto cgrid = [](size_t total) { return dim3((unsigned)((total + 255) / 256)); };
    hipMemsetAsync(qr_bf, 0, (size_t)BSZ * NH * 1024 * 64 * 2, stream);
    hipMemsetAsync(rk_bf, 0, (size_t)NH * RLP * 64 * 2, stream);
    convpad<<<cgrid((size_t)4096 * 384), 256, 0, stream>>>(w, w_bf, 4096, DM, 4096, 384);
    convpad<<<cgrid((size_t)1152 * 384), 256, 0, stream>>>(qkv_w, qkv_bf, H3, DM, 1152, 384);
    convpad<<<cgrid((size_t)2176 * 384), 256, 0, stream>>>(r, r_bf, RLEN, DM, 2176, 384);
    convpad<<<cgrid((size_t)384 * 384), 256, 0, stream>>>(r_w, rw_bf, DM, DM, 384, 384);
    convpad<<<cgrid((size_t)384 * 384), 256, 0, stream>>>(o_w, ow_bf, DM, DM, 384, 384);
    convpad<<<cgrid((size_t)960 * 384), 256, 0, stream>>>(ffw1, f1_bf, DI, DM, 960, 384);
    convpad<<<cgrid((size_t)384 * 928), 256, 0, stream>>>(ffw2, f2_bf, DM, DI, 384, 928);
    init_pads<<<cgrid((size_t)BSZ * NH * 1024 * 2), 256, 0, stream>>>(qwp, Kpp, Vpp, vec_bf);

    // QKV GEMM with scatter epilogue -> qwp / qr_bf / Kpp / Vpp
    gemm_mfma<5><<<dim3(18, 32), 256, 0, stream>>>(w_bf, qkv_bf, rwb, qwp, 4096, H3, 384, 0,
                                                   rrb, (float*)qr_bf, Kpp, Vpp, 0);
    // rk GEMM -> rk_bf  bf16 [n][2112][64]
    gemm_mfma<6><<<dim3(6, 17), 256, 0, stream>>>(r_bf, rw_bf, nullptr, rk_bf, RLEN, DM, 384, 0,
                                                  nullptr, nullptr, nullptr, nullptr, 0);
    if (full) {
        // BDfull = qr @ rk^T; 1-D XCD-grouped grid: 8 * (1056/8) * 10 = 10560
        gemm_mfma<7><<<dim3(10560), 256, 0, stream>>>(
            qr_bf, rk_bf, nullptr, BD, 1024, RLEN, 64, 0,
            nullptr, nullptr, nullptr, nullptr, 0);
        // attn: 8 * (128/8) * 20 = 2560
        attn4<<<dim3(2560), 256, 0, stream>>>(qwp, Kpp, Vpp, BD, relpos,
                                              op_part, ml_part, 0, BSZ);
    } else {
        for (int b = 0; b < BSZ; ++b) {
            gemm_mfma<7><<<dim3(2640), 256, 0, stream>>>(      // 8*(264/8)*10
                qr_bf, rk_bf, nullptr, BD, 1024, RLEN, 64, 0,
                nullptr, nullptr, nullptr, nullptr, b);
            attn4<<<dim3(640), 256, 0, stream>>>(qwp, Kpp, Vpp, BD, relpos,   // 8*(32/8)*20
                                                 op_part, ml_part, b, 1);
        }
    }
    attn_combine<<<cgrid((size_t)BSZ * NH * 1024 * 38), 256, 0, stream>>>(op_part, ml_part, vec_bf);
    // attn_out = vec @ o_w^T   (overwrites op_part alias -- partials are dead)
    gemm_mfma<0><<<dim3(6, 32), 256, 0, stream>>>(vec_bf, ow_bf, nullptr, attnf, 4096, DM, 384, DM,
                                                  nullptr, nullptr, nullptr, nullptr, 0);
    ln_kernel<true><<<4096, 256, 0, stream>>>(w, attnf, ln1g, ln1b, out1f, out1_bf);
    gemm_mfma<3><<<dim3(15, 32), 256, 0, stream>>>(out1_bf, f1_bf, ffb1, h1_bf, 4096, DI, 384, 928,
                                                   nullptr, nullptr, nullptr, nullptr, 0);
    gemm_mfma<4><<<dim3(6, 32), 256, 0, stream>>>(h1_bf, f2_bf, ffb2, core, 4096, DM, 928, DM,
                                                  nullptr, nullptr, nullptr, nullptr, 0);
    ln_kernel<false><<<4096, 256, 0, stream>>>(out1f, core, ln2g, ln2b, out, nullptr);
}

// Round 11
// 405.869 us; speedup vs baseline: 2.1089x; 1.0965x over previous
//
#include <hip/hip_runtime.h>
#include <math.h>

#define QLEN 1024
#define BSZ 4
#define NH 10
#define DH 38
#define DM 380
#define DI 900
#define H3 1140
#define RLEN 2049
#define RLP 2112                      // RLEN padded to 33*64
#define SCALE 0.16222142113076254f   // 1/sqrt(38)
#define KS 2                          // k-splits in attention

typedef unsigned short ushortt;
typedef __attribute__((ext_vector_type(8))) short short8;
typedef __attribute__((ext_vector_type(4))) float float4v;

__device__ __forceinline__ float bf2f(ushortt u) {
    return __uint_as_float(((unsigned int)u) << 16);
}
__device__ __forceinline__ ushortt f2bf(float f) {
    unsigned int u = __float_as_uint(f);
    u += 0x7fffu + ((u >> 16) & 1u);   // RNE
    return (ushortt)(u >> 16);
}

// ---------- f32 [R][C] -> bf16 [Rp][Cp], zero-padded ----------
__global__ __launch_bounds__(256)
void convpad(const float* __restrict__ src, ushortt* __restrict__ dst,
             int R, int C, int Rp, int Cp) {
    const int total = Rp * Cp;
    for (int i = blockIdx.x * 256 + threadIdx.x; i < total; i += gridDim.x * 256) {
        int r = i / Cp, c = i - r * Cp;
        float v = (r < R && c < C) ? src[(size_t)r * C + c] : 0.f;
        dst[i] = f2bf(v);
    }
}

// ---------- zero the pad lanes once per launch ----------
__global__ __launch_bounds__(256)
void init_pads(float* __restrict__ qwp, float* __restrict__ Kp, float* __restrict__ Vp,
               ushortt* __restrict__ vec) {
    const int i = blockIdx.x * 256 + threadIdx.x;
    if (i < BSZ * NH * 1024 * 2) {                       // d=38,39 of the head arrays
        size_t idx = (size_t)(i >> 1) * 40 + 38 + (i & 1);
        qwp[idx] = 0.f; Kp[idx] = 0.f; Vp[idx] = 0.f;
    }
    if (i < 4096 * 4) {                                  // vec cols 380..383
        vec[(size_t)(i >> 2) * 384 + 380 + (i & 3)] = 0;
    }
}

// ---------------- bf16 MFMA GEMM:  C[M,N] = A[M,Kp] * B[N,Kp]^T ----------------
// EPI: 0 = f32 store, 3 = relu(x+bias)->bf16 (ld 928), 4 = x+bias->f32,
//      5 = QKV scatter (qwp f32 + qr_bf bf16[64] + Kp/Vp f32),
//      6 = rk -> rk_bf bf16 [n][2112][64]
template<int EPI>
__global__ __launch_bounds__(256)
void gemm_mfma(const ushortt* __restrict__ A, const ushortt* __restrict__ B,
               const float* __restrict__ bias, void* __restrict__ Cout,
               int M, int N, int Kpp, int ldc,
               const float* __restrict__ bias2, float* __restrict__ out2,
               float* __restrict__ out3, float* __restrict__ out4) {
    __shared__ __align__(16) ushortt As[128 * 32];
    __shared__ __align__(16) ushortt Bs[64 * 32];
    const int tid = threadIdx.x;
    const int wid = tid >> 6, lane = tid & 63;
    const int bRow = blockIdx.y * 128, bCol = blockIdx.x * 64;

    float4v acc[2][4];
    const float4v zz = {0.f, 0.f, 0.f, 0.f};
    #pragma unroll
    for (int m = 0; m < 2; ++m)
        #pragma unroll
        for (int n = 0; n < 4; ++n) acc[m][n] = zz;

    const int arow = tid >> 1, acol = (tid & 1) * 16;
    const int brow = tid >> 2, bcol = (tid & 3) * 8;
    const int fr = lane & 15, kg = lane >> 4;

    for (int k0 = 0; k0 < Kpp; k0 += 32) {
        const ushortt* ag = A + (size_t)(bRow + arow) * Kpp + k0 + acol;
        float4v a0 = *(const float4v*)ag;
        float4v a1 = *(const float4v*)(ag + 8);
        const ushortt* bg = B + (size_t)(bCol + brow) * Kpp + k0 + bcol;
        float4v b0 = *(const float4v*)bg;
        __syncthreads();
        *(float4v*)&As[arow * 32 + acol] = a0;
        *(float4v*)&As[arow * 32 + acol + 8] = a1;
        *(float4v*)&Bs[brow * 32 + bcol] = b0;
        __syncthreads();

        short8 bf[4];
        #pragma unroll
        for (int n = 0; n < 4; ++n)
            bf[n] = *(const short8*)&Bs[(n * 16 + fr) * 32 + kg * 8];
        #pragma unroll
        for (int m = 0; m < 2; ++m) {
            short8 af = *(const short8*)&As[(wid * 32 + m * 16 + fr) * 32 + kg * 8];
            #pragma unroll
            for (int n = 0; n < 4; ++n)
                acc[m][n] = __builtin_amdgcn_mfma_f32_16x16x32_bf16(af, bf[n], acc[m][n], 0, 0, 0);
        }
    }

    #pragma unroll
    for (int m = 0; m < 2; ++m)
        #pragma unroll
        for (int n = 0; n < 4; ++n)
            #pragma unroll
            for (int j = 0; j < 4; ++j) {
                const int row = bRow + wid * 32 + m * 16 + (lane >> 4) * 4 + j;
                const int col = bCol + n * 16 + (lane & 15);
                const float v = acc[m][n][j];
                if (EPI == 0) {
                    if (row < M && col < N) ((float*)Cout)[(size_t)row * ldc + col] = v;
                } else if (EPI == 3) {
                    if (row < M && col < 928) {
                        float h = (col < DI) ? fmaxf(v + bias[col], 0.f) : 0.f;
                        ((ushortt*)Cout)[(size_t)row * 928 + col] = f2bf(h);
                    }
                } else if (EPI == 4) {
                    if (row < M && col < N) ((float*)Cout)[(size_t)row * ldc + col] = v + bias[col];
                } else if (EPI == 5) {
                    if (col < H3) {
                        int part = col / 380;
                        int c = col - part * 380;
                        int nh = c / 38, d = c - nh * 38;
                        int q = row >> 2, b2 = row & 3;
                        size_t idx = (((size_t)b2 * NH + nh) * 1024 + q) * 40 + d;
                        if (part == 0) {
                            ((float*)Cout)[idx] = v + bias[c];                 // qwp (+r_w_bias)
                            ((ushortt*)out2)[(((size_t)b2 * NH + nh) * 1024 + q) * 64 + d]
                                = f2bf(v + bias2[c]);                          // qr_bf (+r_r_bias)
                        } else if (part == 1) out3[idx] = v;                   // Kp
                        else out4[idx] = v;                                    // Vp
                    }
                } else {  // EPI 6
                    if (row < RLEN && col < DM) {
                        int nh = col / 38, d = col - nh * 38;
                        ((ushortt*)Cout)[((size_t)nh * RLP + row) * 64 + d] = f2bf(v);
                    }
                }
            }
}

// ---------------- BD GEMM: all 10 heads per block, coalesced [q][j][n] store -----
// qr: bf16 [b][n][1024][64], rk: bf16 [n][2112][64]
// BD: bf16 [lb][1024 q][2049 j][10 n]; block = 64q x 32j, loops n internally,
// buffers in LDS Call[64][32][10], then streams contiguous 640B/row stores.
__global__ __launch_bounds__(256)
void bd_gemm(const ushortt* __restrict__ qr, const ushortt* __restrict__ rk,
             ushortt* __restrict__ BD, int bofs) {
    __shared__ __align__(16) ushortt As[64][72];   // +8 pad: 2-way banks on reads
    __shared__ __align__(16) ushortt Bs[32][72];
    __shared__ __align__(16) ushortt Call[64 * 32 * 10];
    const int tid = threadIdx.x;
    const int wid = tid >> 6, lane = tid & 63;
    const int jt = blockIdx.x, qt = blockIdx.y, lb = blockIdx.z;
    const int j0 = jt * 32, q0 = qt * 64;
    const int fr = lane & 15, kg = lane >> 4;
    const int jcount = min(32, RLEN - j0);

    for (int n = 0; n < NH; ++n) {
        const ushortt* Ab = qr + (((size_t)(bofs + lb) * NH + n) * 1024 + q0) * 64;
        const ushortt* Bb = rk + ((size_t)n * RLP + j0) * 64;
        __syncthreads();                       // As/Bs free from previous head
        {
            int rr = tid >> 2, cc = (tid & 3) * 16;
            *(float4v*)&As[rr][cc] = *(const float4v*)(Ab + (size_t)rr * 64 + cc);
            *(float4v*)&As[rr][cc + 8] = *(const float4v*)(Ab + (size_t)rr * 64 + cc + 8);
            int br = tid >> 3, bc = (tid & 7) * 8;
            *(float4v*)&Bs[br][bc] = *(const float4v*)(Bb + (size_t)br * 64 + bc);
        }
        __syncthreads();
        float4v acc[2] = {{0.f,0.f,0.f,0.f},{0.f,0.f,0.f,0.f}};
        #pragma unroll
        for (int ks = 0; ks < 64; ks += 32) {
            short8 af = *(const short8*)&As[wid * 16 + fr][ks + kg * 8];
            #pragma unroll
            for (int c = 0; c < 2; ++c) {
                short8 bfr = *(const short8*)&Bs[c * 16 + fr][ks + kg * 8];
                acc[c] = __builtin_amdgcn_mfma_f32_16x16x32_bf16(af, bfr, acc[c], 0, 0, 0);
            }
        }
        #pragma unroll
        for (int c = 0; c < 2; ++c)
            #pragma unroll
            for (int jj = 0; jj < 4; ++jj) {
                int rq = wid * 16 + (lane >> 4) * 4 + jj;
                int cj = c * 16 + (lane & 15);
                Call[(rq * 32 + cj) * 10 + n] = f2bf(acc[c][jj]);
            }
    }
    __syncthreads();
    // coalesced store: per q-row jcount*10 bf16 = jcount*5 dwords (4B-aligned)
    const int rowdw = jcount * 5;
    const unsigned* Cdw = (const unsigned*)Call;
    unsigned* G = (unsigned*)BD;
    for (int idx = tid; idx < 64 * rowdw; idx += 256) {
        int rr = idx / rowdw, rem = idx - rr * rowdw;
        size_t gdw = ((((size_t)lb * 1024 + q0 + rr) * RLEN + j0) * 10) / 2 + rem;
        G[gdw] = Cdw[rr * 160 + rem];
    }
}

// ---------------- split-K fused attention, 32 q-rows per block ----------------
// qwp/Kp/Vp: f32 [b][n][1024][40]; BD: bf16 [lb][1024 q][2049 j][NH]
// 1-D XCD-grouped grid: the 20 (n,s) blocks of each (qc,b) land on ONE XCD so
// they share BD lines + relpos rows in that XCD's L2. Heavy qc dispatch first.
// BD gathers for tile t+1 are issued before tile t's PV (latency hiding).
__global__ __launch_bounds__(256)
void attn4(const float* __restrict__ qwp, const float* __restrict__ Kp,
           const float* __restrict__ Vp, const ushortt* __restrict__ BD,
           const int* __restrict__ relpos,
           float* __restrict__ op, float2* __restrict__ ml, int b0, int nb) {
    const int bid = blockIdx.x;
    const int xcd = bid & 7, t = bid >> 3;
    const int gl = t / 20, member = t - gl * 20;   // member: n + 10*s
    const int G = gl * 8 + xcd;                    // group = (31-qc)*nb + lbd
    const int qc = 31 - G / nb;
    const int lbd = G - (31 - qc) * nb;
    const int n = member % NH, s = member / NH;
    const int qbase = qc * 32;
    const int b = b0 + lbd;
    const int tid = threadIdx.x;
    const int row = tid >> 3, kg = tid & 7;
    const int qi = qbase + row;
    const size_t bn = (size_t)b * NH + n;
    const size_t prow = ((size_t)s * (BSZ * NH) + bn) * 1024 + qi;

    const int ntchunk = (qbase + 95) >> 6;       // ceil((qbase+32)/64)
    const int tbeg = s * 8;                      // KS=2: 8 tiles (=512 k) per split
    const int tend = min(tbeg + 8, ntchunk);
    if (tbeg >= tend) {                          // inactive split
        if (kg == 0) ml[prow] = make_float2(-INFINITY, 0.f);
        return;
    }

    __shared__ __align__(16) float KtL[64 * 40];
    __shared__ __align__(16) float VtL[64 * 40];
    __shared__ float pL[32 * 66];

    const float* Kbase = Kp + bn * 1024 * 40;
    const float* Vbase = Vp + bn * 1024 * 40;

    float4v qw[10];
    {
        const float4v* src = (const float4v*)(qwp + (bn * 1024 + qi) * 40);
        #pragma unroll
        for (int i = 0; i < 10; ++i) qw[i] = src[i];
    }
    float o[5] = {0.f, 0.f, 0.f, 0.f, 0.f};
    float mrun = -INFINITY, lrun = 0.f;
    const int* rp = relpos + ((size_t)b * QLEN + qi) * QLEN;
    const ushortt* bdrow = BD + (((size_t)lbd * 1024 + qi) * RLEN) * NH + n;

    // prime gathers for the first tile
    int jv[8]; float bdv[8];
    {
        const int k0 = tbeg * 64;
        #pragma unroll
        for (int ss = 0; ss < 8; ++ss) {
            const int kk = k0 + kg + ss * 8;
            int j = -1;
            if (kk <= qi) {
                int rpv = rp[kk];
                rpv = rpv < -1024 ? -1024 : (rpv > 1024 ? 1024 : rpv);
                j = 1024 - rpv;
            }
            jv[ss] = j;
        }
        #pragma unroll
        for (int ss = 0; ss < 8; ++ss)
            bdv[ss] = (jv[ss] >= 0) ? bf2f(bdrow[(size_t)jv[ss] * NH]) : 0.f;
    }

    for (int kt = tbeg; kt < tend; ++kt) {
        const int k0 = kt * 64;
        __syncthreads();
        {
            const float4v* ks = (const float4v*)(Kbase + (size_t)k0 * 40);
            const float4v* vs = (const float4v*)(Vbase + (size_t)k0 * 40);
            for (int e = tid; e < 640; e += 256) {
                ((float4v*)KtL)[e] = ks[e];
                ((float4v*)VtL)[e] = vs[e];
            }
        }
        __syncthreads();

        float sarr[8];
        float pmax = -INFINITY;
        #pragma unroll
        for (int ss = 0; ss < 8; ++ss) {
            float sv = -INFINITY;
            if (jv[ss] >= 0) {
                const int k = kg + ss * 8;
                float acc1 = 0.f;
                const float4v* kt4 = (const float4v*)(KtL + k * 40);
                #pragma unroll
                for (int i = 0; i < 10; ++i) {
                    float4v kv = kt4[i];
                    acc1 += qw[i][0] * kv[0] + qw[i][1] * kv[1]
                          + qw[i][2] * kv[2] + qw[i][3] * kv[3];
                }
                sv = (acc1 + bdv[ss]) * SCALE;
            }
            sarr[ss] = sv;
            pmax = fmaxf(pmax, sv);
        }
        pmax = fmaxf(pmax, __shfl_xor(pmax, 1, 64));
        pmax = fmaxf(pmax, __shfl_xor(pmax, 2, 64));
        pmax = fmaxf(pmax, __shfl_xor(pmax, 4, 64));
        const float nm = fmaxf(mrun, pmax);
        const float corr = __expf(mrun - nm);   // first tile: exp(-inf)=0
        float psum = 0.f;
        float* prw = pL + row * 66;
        #pragma unroll
        for (int ss = 0; ss < 8; ++ss) {
            float p = __expf(sarr[ss] - nm);
            psum += p;
            prw[kg + ss * 8] = p;
        }
        psum += __shfl_xor(psum, 1, 64);
        psum += __shfl_xor(psum, 2, 64);
        psum += __shfl_xor(psum, 4, 64);
        lrun = lrun * corr + psum;
        mrun = nm;
        #pragma unroll
        for (int jj = 0; jj < 5; ++jj) o[jj] *= corr;

        // prefetch next tile's j + BD before PV (hides gather latency under PV)
        int jn[8]; float bdn[8];
        if (kt + 1 < tend) {
            const int k0n = (kt + 1) * 64;
            #pragma unroll
            for (int ss = 0; ss < 8; ++ss) {
                const int kk = k0n + kg + ss * 8;
                int j = -1;
                if (kk <= qi) {
                    int rpv = rp[kk];
                    rpv = rpv < -1024 ? -1024 : (rpv > 1024 ? 1024 : rpv);
                    j = 1024 - rpv;
                }
                jn[ss] = j;
            }
            #pragma unroll
            for (int ss = 0; ss < 8; ++ss)
                bdn[ss] = (jn[ss] >= 0) ? bf2f(bdrow[(size_t)jn[ss] * NH]) : 0.f;
        } else {
            #pragma unroll
            for (int ss = 0; ss < 8; ++ss) { jn[ss] = -1; bdn[ss] = 0.f; }
        }

        int kmax = qi - k0 + 1; if (kmax > 64) kmax = 64;
        #pragma unroll 4
        for (int k = 0; k < kmax; ++k) {
            float p = prw[k];
            const float* vr = VtL + k * 40;
            float4v v4 = *(const float4v*)(vr + 4 * kg);
            float v1 = vr[32 + kg];
            o[0] += p * v4[0]; o[1] += p * v4[1];
            o[2] += p * v4[2]; o[3] += p * v4[3];
            o[4] += p * v1;
        }
        #pragma unroll
        for (int ss = 0; ss < 8; ++ss) { jv[ss] = jn[ss]; bdv[ss] = bdn[ss]; }
    }
    float* oprow = op + prow * 40;
    #pragma unroll
    for (int jj = 0; jj < 4; ++jj) oprow[4 * kg + jj] = o[jj];
    oprow[32 + kg] = o[4];
    if (kg == 0) ml[prow] = make_float2(mrun, lrun);
}

// ---------------- combine split-K partials -> vec (bf16) ----------------
__global__ __launch_bounds__(256)
void attn_combine(const float* __restrict__ op, const float2* __restrict__ ml,
                  ushortt* __restrict__ vec) {
    const int idx = blockIdx.x * 256 + threadIdx.x;
    if (idx >= BSZ * NH * 1024 * 38) return;
    const int d = idx % 38;
    const int rh = idx / 38;                 // bn*1024 + q
    const int q = rh & 1023;
    const int bn = rh >> 10;
    const int b = bn / NH, n = bn - b * NH;
    const float2 a = ml[rh];
    const float2 c = ml[(size_t)BSZ * NH * 1024 + rh];
    const float M = fmaxf(a.x, c.x);
    float l = 0.f, o = 0.f;
    if (a.y > 0.f) {
        float w = __expf(a.x - M);
        l += a.y * w;
        o += op[(size_t)rh * 40 + d] * w;
    }
    if (c.y > 0.f) {
        float w = __expf(c.x - M);
        l += c.y * w;
        o += op[((size_t)BSZ * NH * 1024 + rh) * 40 + d] * w;
    }
    vec[((size_t)q * BSZ + b) * 384 + (size_t)n * 38 + d] = f2bf(o / l);
}

// ---------------- residual + LayerNorm ----------------
template<bool WRITE_BF>
__global__ __launch_bounds__(256)
void ln_kernel(const float* __restrict__ x1, const float* __restrict__ x2,
               const float* __restrict__ g, const float* __restrict__ bb,
               float* __restrict__ outf, ushortt* __restrict__ outbf) {
    const int row = blockIdx.x;
    const float* p1 = x1 + (size_t)row * DM;
    const float* p2 = x2 + (size_t)row * DM;
    __shared__ float xb[DM];
    __shared__ float red[256];
    const int tid = threadIdx.x;
    float s = 0.f;
    for (int i = tid; i < DM; i += 256) { float v = p1[i] + p2[i]; xb[i] = v; s += v; }
    red[tid] = s; __syncthreads();
    for (int st = 128; st > 0; st >>= 1) { if (tid < st) red[tid] += red[tid + st]; __syncthreads(); }
    const float mean = red[0] / DM;
    __syncthreads();
    float s2 = 0.f;
    for (int i = tid; i < DM; i += 256) { float d = xb[i] - mean; s2 += d * d; }
    red[tid] = s2; __syncthreads();
    for (int st = 128; st > 0; st >>= 1) { if (tid < st) red[tid] += red[tid + st]; __syncthreads(); }
    const float rstd = rsqrtf(red[0] / DM + 1e-5f);
    for (int i = tid; i < (WRITE_BF ? 384 : DM); i += 256) {
        float v = 0.f;
        if (i < DM) {
            v = (xb[i] - mean) * rstd * g[i] + bb[i];
            outf[(size_t)row * DM + i] = v;
        }
        if (WRITE_BF) outbf[(size_t)row * 384 + i] = f2bf(i < DM ? v : 0.f);
    }
}

extern "C" void kernel_launch(void* const* d_in, const int* in_sizes, int n_in,
                              void* d_out, int out_size, void* d_ws, size_t ws_size,
                              hipStream_t stream) {
    const float* w     = (const float*)d_in[0];
    const float* r     = (const float*)d_in[1];
    const float* rwb   = (const float*)d_in[2];
    const float* rrb   = (const float*)d_in[3];
    const float* qkv_w = (const float*)d_in[4];
    const float* r_w   = (const float*)d_in[5];
    const float* o_w   = (const float*)d_in[6];
    const float* ln1g  = (const float*)d_in[7];
    const float* ln1b  = (const float*)d_in[8];
    const float* ffw1  = (const float*)d_in[9];
    const float* ffb1  = (const float*)d_in[10];
    const float* ffw2  = (const float*)d_in[11];
    const float* ffb2  = (const float*)d_in[12];
    const float* ln2g  = (const float*)d_in[13];
    const float* ln2b  = (const float*)d_in[14];
    const int*   relpos = (const int*)d_in[16];
    float* out = (float*)d_out;

    char* cur = (char*)d_ws;
    auto alloc = [&](size_t bytes) { char* p = cur; cur += (bytes + 255) & ~(size_t)255; return p; };
    ushortt* w_bf    = (ushortt*)alloc((size_t)4096 * 384 * 2);
    ushortt* qkv_bf  = (ushortt*)alloc((size_t)1152 * 384 * 2);
    ushortt* r_bf    = (ushortt*)alloc((size_t)2176 * 384 * 2);
    ushortt* rw_bf   = (ushortt*)alloc((size_t)384 * 384 * 2);
    ushortt* ow_bf   = (ushortt*)alloc((size_t)384 * 384 * 2);
    ushortt* f1_bf   = (ushortt*)alloc((size_t)960 * 384 * 2);
    ushortt* f2_bf   = (ushortt*)alloc((size_t)384 * 928 * 2);
    float*   qwp     = (float*)alloc((size_t)BSZ * NH * 1024 * 40 * 4);
    float*   Kpp     = (float*)alloc((size_t)BSZ * NH * 1024 * 40 * 4);
    float*   Vpp     = (float*)alloc((size_t)BSZ * NH * 1024 * 40 * 4);
    ushortt* qr_bf   = (ushortt*)alloc((size_t)BSZ * NH * 1024 * 64 * 2);
    ushortt* rk_bf   = (ushortt*)alloc((size_t)NH * RLP * 64 * 2);
    ushortt* vec_bf  = (ushortt*)alloc((size_t)4096 * 384 * 2);
    ushortt* out1_bf = (ushortt*)alloc((size_t)4096 * 384 * 2);
    ushortt* h1_bf   = (ushortt*)alloc((size_t)4096 * 928 * 2);
    float*   attnf   = (float*)alloc((size_t)4096 * DM * 4);
    float*   out1f   = (float*)alloc((size_t)4096 * DM * 4);
    float*   core    = (float*)alloc((size_t)4096 * DM * 4);

    // split-K partials alias attnf/out1f/core (dead until after combine)
    float*  op_part = attnf;
    float2* ml_part = (float2*)(attnf + (size_t)KS * BSZ * NH * 1024 * 40);

    // BD buffer: bf16 [lb][1024 q][2049 j][NH]
    const size_t bd_b_bytes = (size_t)1024 * RLEN * NH * 2;   // per-b: ~41 MB
    ushortt* BD = (ushortt*)alloc(bd_b_bytes * BSZ);
    bool full = ((size_t)(cur - (char*)d_ws) <= ws_size);
    if (!full) { cur = (char*)BD; BD = (ushortt*)alloc(bd_b_bytes); }  // per-b reuse

    auto cgrid = [](size_t total) { return dim3((unsigned)((total + 255) / 256)); };
    hipMemsetAsync(qr_bf, 0, (size_t)BSZ * NH * 1024 * 64 * 2, stream);
    hipMemsetAsync(rk_bf, 0, (size_t)NH * RLP * 64 * 2, stream);
    convpad<<<cgrid((size_t)4096 * 384), 256, 0, stream>>>(w, w_bf, 4096, DM, 4096, 384);
    convpad<<<cgrid((size_t)1152 * 384), 256, 0, stream>>>(qkv_w, qkv_bf, H3, DM, 1152, 384);
    convpad<<<cgrid((size_t)2176 * 384), 256, 0, stream>>>(r, r_bf, RLEN, DM, 2176, 384);
    convpad<<<cgrid((size_t)384 * 384), 256, 0, stream>>>(r_w, rw_bf, DM, DM, 384, 384);
    convpad<<<cgrid((size_t)384 * 384), 256, 0, stream>>>(o_w, ow_bf, DM, DM, 384, 384);
    convpad<<<cgrid((size_t)960 * 384), 256, 0, stream>>>(ffw1, f1_bf, DI, DM, 960, 384);
    convpad<<<cgrid((size_t)384 * 928), 256, 0, stream>>>(ffw2, f2_bf, DM, DI, 384, 928);
    init_pads<<<cgrid((size_t)BSZ * NH * 1024 * 2), 256, 0, stream>>>(qwp, Kpp, Vpp, vec_bf);

    // QKV GEMM with scatter epilogue -> qwp / qr_bf / Kpp / Vpp
    gemm_mfma<5><<<dim3(18, 32), 256, 0, stream>>>(w_bf, qkv_bf, rwb, qwp, 4096, H3, 384, 0,
                                                   rrb, (float*)qr_bf, Kpp, Vpp);
    // rk GEMM -> rk_bf  bf16 [n][2112][64]
    gemm_mfma<6><<<dim3(6, 17), 256, 0, stream>>>(r_bf, rw_bf, nullptr, rk_bf, RLEN, DM, 384, 0,
                                                  nullptr, nullptr, nullptr, nullptr);
    if (full) {
        // BD = qr @ rk^T, all heads per block, coalesced store
        bd_gemm<<<dim3(65, 16, BSZ), 256, 0, stream>>>(qr_bf, rk_bf, BD, 0);
        // attn: 8 * (128/8) * 20 = 2560, XCD-grouped
        attn4<<<dim3(2560), 256, 0, stream>>>(qwp, Kpp, Vpp, BD, relpos,
                                              op_part, ml_part, 0, BSZ);
    } else {
        for (int b = 0; b < BSZ; ++b) {
            bd_gemm<<<dim3(65, 16, 1), 256, 0, stream>>>(qr_bf, rk_bf, BD, b);
            attn4<<<dim3(640), 256, 0, stream>>>(qwp, Kpp, Vpp, BD, relpos,   // 8*(32/8)*20
                                                 op_part, ml_part, b, 1);
        }
    }
    attn_combine<<<cgrid((size_t)BSZ * NH * 1024 * 38), 256, 0, stream>>>(op_part, ml_part, vec_bf);
    // attn_out = vec @ o_w^T   (overwrites op_part alias -- partials are dead)
    gemm_mfma<0><<<dim3(6, 32), 256, 0, stream>>>(vec_bf, ow_bf, nullptr, attnf, 4096, DM, 384, DM,
                                                  nullptr, nullptr, nullptr, nullptr);
    ln_kernel<true><<<4096, 256, 0, stream>>>(w, attnf, ln1g, ln1b, out1f, out1_bf);
    gemm_mfma<3><<<dim3(15, 32), 256, 0, stream>>>(out1_bf, f1_bf, ffb1, h1_bf, 4096, DI, 384, 928,
                                                   nullptr, nullptr, nullptr, nullptr);
    gemm_mfma<4><<<dim3(6, 32), 256, 0, stream>>>(h1_bf, f2_bf, ffb2, core, 4096, DM, 928, DM,
                                                  nullptr, nullptr, nullptr, nullptr);
    ln_kernel<false><<<4096, 256, 0, stream>>>(out1f, core, ln2g, ln2b, out, nullptr);
}

// Round 12
// 402.428 us; speedup vs baseline: 2.1269x; 1.0086x over previous
//
#include <hip/hip_runtime.h>
#include <math.h>

#define QLEN 1024
#define BSZ 4
#define NH 10
#define DH 38
#define DM 380
#define DI 900
#define H3 1140
#define RLEN 2049
#define RLP 2112                      // RLEN padded to 33*64
#define SCALE 0.16222142113076254f   // 1/sqrt(38)

typedef unsigned short ushortt;
typedef __attribute__((ext_vector_type(8))) short short8;
typedef __attribute__((ext_vector_type(4))) float float4v;

__device__ __forceinline__ float bf2f(ushortt u) {
    return __uint_as_float(((unsigned int)u) << 16);
}
__device__ __forceinline__ ushortt f2bf(float f) {
    unsigned int u = __float_as_uint(f);
    u += 0x7fffu + ((u >> 16) & 1u);   // RNE
    return (ushortt)(u >> 16);
}

// ---------- f32 [R][C] -> bf16 [Rp][Cp], zero-padded ----------
__global__ __launch_bounds__(256)
void convpad(const float* __restrict__ src, ushortt* __restrict__ dst,
             int R, int C, int Rp, int Cp) {
    const int total = Rp * Cp;
    for (int i = blockIdx.x * 256 + threadIdx.x; i < total; i += gridDim.x * 256) {
        int r = i / Cp, c = i - r * Cp;
        float v = (r < R && c < C) ? src[(size_t)r * C + c] : 0.f;
        dst[i] = f2bf(v);
    }
}

// ---------- zero the pad lanes once per launch ----------
__global__ __launch_bounds__(256)
void init_pads(float* __restrict__ qwp, ushortt* __restrict__ Kb, ushortt* __restrict__ Vb,
               ushortt* __restrict__ vec) {
    const int i = blockIdx.x * 256 + threadIdx.x;
    if (i < BSZ * NH * 1024 * 2) {                       // d=38,39 of the head arrays
        size_t idx = (size_t)(i >> 1) * 40 + 38 + (i & 1);
        qwp[idx] = 0.f; Kb[idx] = 0; Vb[idx] = 0;
    }
    if (i < 4096 * 4) {                                  // vec cols 380..383
        vec[(size_t)(i >> 2) * 384 + 380 + (i & 3)] = 0;
    }
}

// ---------------- bf16 MFMA GEMM:  C[M,N] = A[M,Kp] * B[N,Kp]^T ----------------
// EPI: 0 = f32 store, 3 = relu(x+bias)->bf16 (ld 928), 4 = x+bias->f32,
//      5 = QKV scatter (qwp f32 + qr_bf bf16[64] + K_bf/V_bf bf16[40]),
//      6 = rk -> rk_bf bf16 [n][2112][64]
template<int EPI>
__global__ __launch_bounds__(256)
void gemm_mfma(const ushortt* __restrict__ A, const ushortt* __restrict__ B,
               const float* __restrict__ bias, void* __restrict__ Cout,
               int M, int N, int Kpp, int ldc,
               const float* __restrict__ bias2, float* __restrict__ out2,
               float* __restrict__ out3, float* __restrict__ out4) {
    __shared__ __align__(16) ushortt As[128 * 32];
    __shared__ __align__(16) ushortt Bs[64 * 32];
    const int tid = threadIdx.x;
    const int wid = tid >> 6, lane = tid & 63;
    const int bRow = blockIdx.y * 128, bCol = blockIdx.x * 64;

    float4v acc[2][4];
    const float4v zz = {0.f, 0.f, 0.f, 0.f};
    #pragma unroll
    for (int m = 0; m < 2; ++m)
        #pragma unroll
        for (int n = 0; n < 4; ++n) acc[m][n] = zz;

    const int arow = tid >> 1, acol = (tid & 1) * 16;
    const int brow = tid >> 2, bcol = (tid & 3) * 8;
    const int fr = lane & 15, kg = lane >> 4;

    for (int k0 = 0; k0 < Kpp; k0 += 32) {
        const ushortt* ag = A + (size_t)(bRow + arow) * Kpp + k0 + acol;
        float4v a0 = *(const float4v*)ag;
        float4v a1 = *(const float4v*)(ag + 8);
        const ushortt* bg = B + (size_t)(bCol + brow) * Kpp + k0 + bcol;
        float4v b0 = *(const float4v*)bg;
        __syncthreads();
        *(float4v*)&As[arow * 32 + acol] = a0;
        *(float4v*)&As[arow * 32 + acol + 8] = a1;
        *(float4v*)&Bs[brow * 32 + bcol] = b0;
        __syncthreads();

        short8 bf[4];
        #pragma unroll
        for (int n = 0; n < 4; ++n)
            bf[n] = *(const short8*)&Bs[(n * 16 + fr) * 32 + kg * 8];
        #pragma unroll
        for (int m = 0; m < 2; ++m) {
            short8 af = *(const short8*)&As[(wid * 32 + m * 16 + fr) * 32 + kg * 8];
            #pragma unroll
            for (int n = 0; n < 4; ++n)
                acc[m][n] = __builtin_amdgcn_mfma_f32_16x16x32_bf16(af, bf[n], acc[m][n], 0, 0, 0);
        }
    }

    #pragma unroll
    for (int m = 0; m < 2; ++m)
        #pragma unroll
        for (int n = 0; n < 4; ++n)
            #pragma unroll
            for (int j = 0; j < 4; ++j) {
                const int row = bRow + wid * 32 + m * 16 + (lane >> 4) * 4 + j;
                const int col = bCol + n * 16 + (lane & 15);
                const float v = acc[m][n][j];
                if (EPI == 0) {
                    if (row < M && col < N) ((float*)Cout)[(size_t)row * ldc + col] = v;
                } else if (EPI == 3) {
                    if (row < M && col < 928) {
                        float h = (col < DI) ? fmaxf(v + bias[col], 0.f) : 0.f;
                        ((ushortt*)Cout)[(size_t)row * 928 + col] = f2bf(h);
                    }
                } else if (EPI == 4) {
                    if (row < M && col < N) ((float*)Cout)[(size_t)row * ldc + col] = v + bias[col];
                } else if (EPI == 5) {
                    if (col < H3) {
                        int part = col / 380;
                        int c = col - part * 380;
                        int nh = c / 38, d = c - nh * 38;
                        int q = row >> 2, b2 = row & 3;
                        size_t idx = (((size_t)b2 * NH + nh) * 1024 + q) * 40 + d;
                        if (part == 0) {
                            ((float*)Cout)[idx] = v + bias[c];                 // qwp (+r_w_bias)
                            ((ushortt*)out2)[(((size_t)b2 * NH + nh) * 1024 + q) * 64 + d]
                                = f2bf(v + bias2[c]);                          // qr_bf (+r_r_bias)
                        } else if (part == 1) ((ushortt*)out3)[idx] = f2bf(v); // K_bf
                        else ((ushortt*)out4)[idx] = f2bf(v);                  // V_bf
                    }
                } else {  // EPI 6
                    if (row < RLEN && col < DM) {
                        int nh = col / 38, d = col - nh * 38;
                        ((ushortt*)Cout)[((size_t)nh * RLP + row) * 64 + d] = f2bf(v);
                    }
                }
            }
}

// ---------------- BD GEMM: all 10 heads per block, coalesced [q][j][n] store -----
__global__ __launch_bounds__(256)
void bd_gemm(const ushortt* __restrict__ qr, const ushortt* __restrict__ rk,
             ushortt* __restrict__ BD, int bofs) {
    __shared__ __align__(16) ushortt As[64][72];
    __shared__ __align__(16) ushortt Bs[32][72];
    __shared__ __align__(16) ushortt Call[64 * 32 * 10];
    const int tid = threadIdx.x;
    const int wid = tid >> 6, lane = tid & 63;
    const int jt = blockIdx.x, qt = blockIdx.y, lb = blockIdx.z;
    const int j0 = jt * 32, q0 = qt * 64;
    const int fr = lane & 15, kg = lane >> 4;
    const int jcount = min(32, RLEN - j0);

    for (int n = 0; n < NH; ++n) {
        const ushortt* Ab = qr + (((size_t)(bofs + lb) * NH + n) * 1024 + q0) * 64;
        const ushortt* Bb = rk + ((size_t)n * RLP + j0) * 64;
        __syncthreads();
        {
            int rr = tid >> 2, cc = (tid & 3) * 16;
            *(float4v*)&As[rr][cc] = *(const float4v*)(Ab + (size_t)rr * 64 + cc);
            *(float4v*)&As[rr][cc + 8] = *(const float4v*)(Ab + (size_t)rr * 64 + cc + 8);
            int br = tid >> 3, bc = (tid & 7) * 8;
            *(float4v*)&Bs[br][bc] = *(const float4v*)(Bb + (size_t)br * 64 + bc);
        }
        __syncthreads();
        float4v acc[2] = {{0.f,0.f,0.f,0.f},{0.f,0.f,0.f,0.f}};
        #pragma unroll
        for (int ks = 0; ks < 64; ks += 32) {
            short8 af = *(const short8*)&As[wid * 16 + fr][ks + kg * 8];
            #pragma unroll
            for (int c = 0; c < 2; ++c) {
                short8 bfr = *(const short8*)&Bs[c * 16 + fr][ks + kg * 8];
                acc[c] = __builtin_amdgcn_mfma_f32_16x16x32_bf16(af, bfr, acc[c], 0, 0, 0);
            }
        }
        #pragma unroll
        for (int c = 0; c < 2; ++c)
            #pragma unroll
            for (int jj = 0; jj < 4; ++jj) {
                int rq = wid * 16 + (lane >> 4) * 4 + jj;
                int cj = c * 16 + (lane & 15);
                Call[(rq * 32 + cj) * 10 + n] = f2bf(acc[c][jj]);
            }
    }
    __syncthreads();
    const int rowdw = jcount * 5;
    const unsigned* Cdw = (const unsigned*)Call;
    unsigned* G = (unsigned*)BD;
    for (int idx = tid; idx < 64 * rowdw; idx += 256) {
        int rr = idx / rowdw, rem = idx - rr * rowdw;
        size_t gdw = ((((size_t)lb * 1024 + q0 + rr) * RLEN + j0) * 10) / 2 + rem;
        G[gdw] = Cdw[rr * 160 + rem];
    }
}

// ---------------- balanced split-K fused attention, 32 q-rows per block -------
// qwp f32 / K_bf,V_bf bf16: [b][n][1024][40]; BD: bf16 [lb][1024 q][2049 j][NH]
// Work item = (qc, b, s) with <=4 tiles; ns(qc) = (qc>>3)+1 splits.
// 1-D XCD-grouped grid: 10 head-members per (qc,b,s) group land on ONE XCD.
__global__ __launch_bounds__(256)
void attn5(const float* __restrict__ qwp, const ushortt* __restrict__ Kp,
           const ushortt* __restrict__ Vp, const ushortt* __restrict__ BD,
           const int* __restrict__ relpos,
           ushortt* __restrict__ op, float2* __restrict__ ml, int b0, int nb) {
    const int bid = blockIdx.x;
    const int xcd = bid & 7, t = bid >> 3;
    const int gl = t / 10, n = t - gl * 10;
    const int G = gl * 8 + xcd;                // 0 .. 80*nb-1, heavy-first
    int qc, lb, s;
    {
        const int c3 = 32 * nb, c2 = 24 * nb, c1 = 16 * nb;
        if (G < c3)                { qc = 31 - G / (4 * nb); int r2 = G % (4 * nb); lb = r2 >> 2; s = r2 & 3; }
        else if (G < c3 + c2)      { int l2 = G - c3; qc = 23 - l2 / (3 * nb); int r2 = l2 % (3 * nb); lb = r2 / 3; s = r2 % 3; }
        else if (G < c3 + c2 + c1) { int l2 = G - c3 - c2; qc = 15 - l2 / (2 * nb); int r2 = l2 % (2 * nb); lb = r2 >> 1; s = r2 & 1; }
        else                       { int l2 = G - c3 - c2 - c1; qc = 7 - l2 / nb; lb = l2 % nb; s = 0; }
    }
    const int qbase = qc * 32;
    const int b = b0 + lb;
    const int tid = threadIdx.x;
    const int row = tid >> 3, kg = tid & 7;
    const int qi = qbase + row;
    const size_t bn = (size_t)b * NH + n;
    const size_t prow = ((size_t)s * (BSZ * NH) + bn) * 1024 + qi;

    const int ntiles = (qbase + 95) >> 6;
    const int tbeg = s * 4;
    const int tend = min(tbeg + 4, ntiles);    // always tbeg < tend by construction

    __shared__ __align__(16) float KtL[64 * 40];
    __shared__ __align__(16) float VtL[64 * 40];
    __shared__ float pL[32 * 66];

    const ushortt* Kbase = Kp + bn * 1024 * 40;
    const ushortt* Vbase = Vp + bn * 1024 * 40;

    float4v qw[10];
    {
        const float4v* src = (const float4v*)(qwp + (bn * 1024 + qi) * 40);
        #pragma unroll
        for (int i = 0; i < 10; ++i) qw[i] = src[i];
    }
    float o[5] = {0.f, 0.f, 0.f, 0.f, 0.f};
    float mrun = -INFINITY, lrun = 0.f;
    const int* rp = relpos + ((size_t)b * QLEN + qi) * QLEN;
    const ushortt* bdrow = BD + (((size_t)lb * 1024 + qi) * RLEN) * NH + n;

    for (int kt = tbeg; kt < tend; ++kt) {
        const int k0 = kt * 64;
        __syncthreads();
        {
            const short8* ks = (const short8*)(Kbase + (size_t)k0 * 40);
            const short8* vs = (const short8*)(Vbase + (size_t)k0 * 40);
            for (int e = tid; e < 320; e += 256) {
                short8 kv = ks[e], vv = vs[e];
                float4v k0v, k1v, v0v, v1v;
                #pragma unroll
                for (int x = 0; x < 4; ++x) {
                    k0v[x] = bf2f((ushortt)kv[x]);     k1v[x] = bf2f((ushortt)kv[4 + x]);
                    v0v[x] = bf2f((ushortt)vv[x]);     v1v[x] = bf2f((ushortt)vv[4 + x]);
                }
                ((float4v*)KtL)[e * 2] = k0v; ((float4v*)KtL)[e * 2 + 1] = k1v;
                ((float4v*)VtL)[e * 2] = v0v; ((float4v*)VtL)[e * 2 + 1] = v1v;
            }
        }
        __syncthreads();

        int jv[8];
        #pragma unroll
        for (int ss = 0; ss < 8; ++ss) {
            const int kk = k0 + kg + ss * 8;
            int j = -1;
            if (kk <= qi) {
                int rpv = rp[kk];
                rpv = rpv < -1024 ? -1024 : (rpv > 1024 ? 1024 : rpv);
                j = 1024 - rpv;
            }
            jv[ss] = j;
        }
        float bdv[8];
        #pragma unroll
        for (int ss = 0; ss < 8; ++ss)
            bdv[ss] = (jv[ss] >= 0) ? bf2f(bdrow[(size_t)jv[ss] * NH]) : 0.f;

        float sarr[8];
        float pmax = -INFINITY;
        #pragma unroll
        for (int ss = 0; ss < 8; ++ss) {
            float sv = -INFINITY;
            if (jv[ss] >= 0) {
                const int k = kg + ss * 8;
                float acc1 = 0.f;
                const float4v* kt4 = (const float4v*)(KtL + k * 40);
                #pragma unroll
                for (int i = 0; i < 10; ++i) {
                    float4v kv = kt4[i];
                    acc1 += qw[i][0] * kv[0] + qw[i][1] * kv[1]
                          + qw[i][2] * kv[2] + qw[i][3] * kv[3];
                }
                sv = (acc1 + bdv[ss]) * SCALE;
            }
            sarr[ss] = sv;
            pmax = fmaxf(pmax, sv);
        }
        pmax = fmaxf(pmax, __shfl_xor(pmax, 1, 64));
        pmax = fmaxf(pmax, __shfl_xor(pmax, 2, 64));
        pmax = fmaxf(pmax, __shfl_xor(pmax, 4, 64));
        const float nm = fmaxf(mrun, pmax);
        const float corr = __expf(mrun - nm);   // first tile: exp(-inf)=0
        float psum = 0.f;
        float* prw = pL + row * 66;
        #pragma unroll
        for (int ss = 0; ss < 8; ++ss) {
            float p = __expf(sarr[ss] - nm);
            psum += p;
            prw[kg + ss * 8] = p;
        }
        psum += __shfl_xor(psum, 1, 64);
        psum += __shfl_xor(psum, 2, 64);
        psum += __shfl_xor(psum, 4, 64);
        lrun = lrun * corr + psum;
        mrun = nm;
        #pragma unroll
        for (int jj = 0; jj < 5; ++jj) o[jj] *= corr;
        int kmax = qi - k0 + 1; if (kmax > 64) kmax = 64;
        #pragma unroll 4
        for (int k = 0; k < kmax; ++k) {
            float p = prw[k];
            const float* vr = VtL + k * 40;
            float4v v4 = *(const float4v*)(vr + 4 * kg);
            float v1 = vr[32 + kg];
            o[0] += p * v4[0]; o[1] += p * v4[1];
            o[2] += p * v4[2]; o[3] += p * v4[3];
            o[4] += p * v1;
        }
    }
    ushortt* oprow = op + prow * 40;
    #pragma unroll
    for (int jj = 0; jj < 4; ++jj) oprow[4 * kg + jj] = f2bf(o[jj]);
    oprow[32 + kg] = f2bf(o[4]);
    if (kg == 0) ml[prow] = make_float2(mrun, lrun);
}

// ---------------- combine split partials -> vec (bf16) ----------------
__global__ __launch_bounds__(256)
void attn_combine(const ushortt* __restrict__ op, const float2* __restrict__ ml,
                  ushortt* __restrict__ vec) {
    const int idx = blockIdx.x * 256 + threadIdx.x;
    if (idx >= BSZ * NH * 1024 * 38) return;
    const int d = idx % 38;
    const int rh = idx / 38;                 // bn*1024 + q
    const int q = rh & 1023;
    const int bn = rh >> 10;
    const int b = bn / NH, n = bn - b * NH;
    const int ns = ((q >> 5) >> 3) + 1;      // splits for this q's chunk
    const size_t stride = (size_t)BSZ * NH * 1024;
    float M = -INFINITY;
    float2 mv[4];
    for (int sp = 0; sp < ns; ++sp) {
        mv[sp] = ml[sp * stride + rh];
        M = fmaxf(M, mv[sp].x);
    }
    float l = 0.f, o = 0.f;
    for (int sp = 0; sp < ns; ++sp) {
        float w = __expf(mv[sp].x - M);
        l += mv[sp].y * w;
        o += bf2f(op[(sp * stride + rh) * 40 + d]) * w;
    }
    vec[((size_t)q * BSZ + b) * 384 + (size_t)n * 38 + d] = f2bf(o / l);
}

// ---------------- residual + LayerNorm ----------------
template<bool WRITE_BF>
__global__ __launch_bounds__(256)
void ln_kernel(const float* __restrict__ x1, const float* __restrict__ x2,
               const float* __restrict__ g, const float* __restrict__ bb,
               float* __restrict__ outf, ushortt* __restrict__ outbf) {
    const int row = blockIdx.x;
    const float* p1 = x1 + (size_t)row * DM;
    const float* p2 = x2 + (size_t)row * DM;
    __shared__ float xb[DM];
    __shared__ float red[256];
    const int tid = threadIdx.x;
    float s = 0.f;
    for (int i = tid; i < DM; i += 256) { float v = p1[i] + p2[i]; xb[i] = v; s += v; }
    red[tid] = s; __syncthreads();
    for (int st = 128; st > 0; st >>= 1) { if (tid < st) red[tid] += red[tid + st]; __syncthreads(); }
    const float mean = red[0] / DM;
    __syncthreads();
    float s2 = 0.f;
    for (int i = tid; i < DM; i += 256) { float d = xb[i] - mean; s2 += d * d; }
    red[tid] = s2; __syncthreads();
    for (int st = 128; st > 0; st >>= 1) { if (tid < st) red[tid] += red[tid + st]; __syncthreads(); }
    const float rstd = rsqrtf(red[0] / DM + 1e-5f);
    for (int i = tid; i < (WRITE_BF ? 384 : DM); i += 256) {
        float v = 0.f;
        if (i < DM) {
            v = (xb[i] - mean) * rstd * g[i] + bb[i];
            outf[(size_t)row * DM + i] = v;
        }
        if (WRITE_BF) outbf[(size_t)row * 384 + i] = f2bf(i < DM ? v : 0.f);
    }
}

extern "C" void kernel_launch(void* const* d_in, const int* in_sizes, int n_in,
                              void* d_out, int out_size, void* d_ws, size_t ws_size,
                              hipStream_t stream) {
    const float* w     = (const float*)d_in[0];
    const float* r     = (const float*)d_in[1];
    const float* rwb   = (const float*)d_in[2];
    const float* rrb   = (const float*)d_in[3];
    const float* qkv_w = (const float*)d_in[4];
    const float* r_w   = (const float*)d_in[5];
    const float* o_w   = (const float*)d_in[6];
    const float* ln1g  = (const float*)d_in[7];
    const float* ln1b  = (const float*)d_in[8];
    const float* ffw1  = (const float*)d_in[9];
    const float* ffb1  = (const float*)d_in[10];
    const float* ffw2  = (const float*)d_in[11];
    const float* ffb2  = (const float*)d_in[12];
    const float* ln2g  = (const float*)d_in[13];
    const float* ln2b  = (const float*)d_in[14];
    const int*   relpos = (const int*)d_in[16];
    float* out = (float*)d_out;

    char* cur = (char*)d_ws;
    auto alloc = [&](size_t bytes) { char* p = cur; cur += (bytes + 255) & ~(size_t)255; return p; };
    ushortt* w_bf    = (ushortt*)alloc((size_t)4096 * 384 * 2);
    ushortt* qkv_bf  = (ushortt*)alloc((size_t)1152 * 384 * 2);
    ushortt* r_bf    = (ushortt*)alloc((size_t)2176 * 384 * 2);
    ushortt* rw_bf   = (ushortt*)alloc((size_t)384 * 384 * 2);
    ushortt* ow_bf   = (ushortt*)alloc((size_t)384 * 384 * 2);
    ushortt* f1_bf   = (ushortt*)alloc((size_t)960 * 384 * 2);
    ushortt* f2_bf   = (ushortt*)alloc((size_t)384 * 928 * 2);
    float*   qwp     = (float*)alloc((size_t)BSZ * NH * 1024 * 40 * 4);
    ushortt* K_bf    = (ushortt*)alloc((size_t)BSZ * NH * 1024 * 40 * 2);
    ushortt* V_bf    = (ushortt*)alloc((size_t)BSZ * NH * 1024 * 40 * 2);
    ushortt* qr_bf   = (ushortt*)alloc((size_t)BSZ * NH * 1024 * 64 * 2);
    ushortt* rk_bf   = (ushortt*)alloc((size_t)NH * RLP * 64 * 2);
    ushortt* vec_bf  = (ushortt*)alloc((size_t)4096 * 384 * 2);
    ushortt* out1_bf = (ushortt*)alloc((size_t)4096 * 384 * 2);
    ushortt* h1_bf   = (ushortt*)alloc((size_t)4096 * 928 * 2);
    float*   attnf   = (float*)alloc((size_t)4096 * DM * 4);
    float*   out1f   = (float*)alloc((size_t)4096 * DM * 4);
    float*   core    = (float*)alloc((size_t)4096 * DM * 4);

    // split partials alias attnf/out1f/core (dead until after combine):
    // op bf16 [4][40][1024][40] = 13.11MB + ml float2 [4][40][1024] = 1.31MB < 18.67MB
    ushortt* op_part = (ushortt*)attnf;
    float2*  ml_part = (float2*)((char*)attnf + (size_t)4 * BSZ * NH * 1024 * 40 * 2);

    // BD buffer: bf16 [lb][1024 q][2049 j][NH]
    const size_t bd_b_bytes = (size_t)1024 * RLEN * NH * 2;   // per-b: ~41 MB
    ushortt* BD = (ushortt*)alloc(bd_b_bytes * BSZ);
    bool full = ((size_t)(cur - (char*)d_ws) <= ws_size);
    if (!full) { cur = (char*)BD; BD = (ushortt*)alloc(bd_b_bytes); }  // per-b reuse

    auto cgrid = [](size_t total) { return dim3((unsigned)((total + 255) / 256)); };
    hipMemsetAsync(qr_bf, 0, (size_t)BSZ * NH * 1024 * 64 * 2, stream);
    hipMemsetAsync(rk_bf, 0, (size_t)NH * RLP * 64 * 2, stream);
    convpad<<<cgrid((size_t)4096 * 384), 256, 0, stream>>>(w, w_bf, 4096, DM, 4096, 384);
    convpad<<<cgrid((size_t)1152 * 384), 256, 0, stream>>>(qkv_w, qkv_bf, H3, DM, 1152, 384);
    convpad<<<cgrid((size_t)2176 * 384), 256, 0, stream>>>(r, r_bf, RLEN, DM, 2176, 384);
    convpad<<<cgrid((size_t)384 * 384), 256, 0, stream>>>(r_w, rw_bf, DM, DM, 384, 384);
    convpad<<<cgrid((size_t)384 * 384), 256, 0, stream>>>(o_w, ow_bf, DM, DM, 384, 384);
    convpad<<<cgrid((size_t)960 * 384), 256, 0, stream>>>(ffw1, f1_bf, DI, DM, 960, 384);
    convpad<<<cgrid((size_t)384 * 928), 256, 0, stream>>>(ffw2, f2_bf, DM, DI, 384, 928);
    init_pads<<<cgrid((size_t)BSZ * NH * 1024 * 2), 256, 0, stream>>>(qwp, K_bf, V_bf, vec_bf);

    // QKV GEMM with scatter epilogue -> qwp / qr_bf / K_bf / V_bf
    gemm_mfma<5><<<dim3(18, 32), 256, 0, stream>>>(w_bf, qkv_bf, rwb, qwp, 4096, H3, 384, 0,
                                                   rrb, (float*)qr_bf, (float*)K_bf, (float*)V_bf);
    // rk GEMM -> rk_bf  bf16 [n][2112][64]
    gemm_mfma<6><<<dim3(6, 17), 256, 0, stream>>>(r_bf, rw_bf, nullptr, rk_bf, RLEN, DM, 384, 0,
                                                  nullptr, nullptr, nullptr, nullptr);
    if (full) {
        bd_gemm<<<dim3(65, 16, BSZ), 256, 0, stream>>>(qr_bf, rk_bf, BD, 0);
        attn5<<<dim3(3200), 256, 0, stream>>>(qwp, K_bf, V_bf, BD, relpos,
                                              op_part, ml_part, 0, BSZ);
    } else {
        for (int b = 0; b < BSZ; ++b) {
            bd_gemm<<<dim3(65, 16, 1), 256, 0, stream>>>(qr_bf, rk_bf, BD, b);
            attn5<<<dim3(800), 256, 0, stream>>>(qwp, K_bf, V_bf, BD, relpos,
                                                 op_part, ml_part, b, 1);
        }
    }
    attn_combine<<<cgrid((size_t)BSZ * NH * 1024 * 38), 256, 0, stream>>>(op_part, ml_part, vec_bf);
    // attn_out = vec @ o_w^T   (overwrites op_part alias -- partials are dead)
    gemm_mfma<0><<<dim3(6, 32), 256, 0, stream>>>(vec_bf, ow_bf, nullptr, attnf, 4096, DM, 384, DM,
                                                  nullptr, nullptr, nullptr, nullptr);
    ln_kernel<true><<<4096, 256, 0, stream>>>(w, attnf, ln1g, ln1b, out1f, out1_bf);
    gemm_mfma<3><<<dim3(15, 32), 256, 0, stream>>>(out1_bf, f1_bf, ffb1, h1_bf, 4096, DI, 384, 928,
                                                   nullptr, nullptr, nullptr, nullptr);
    gemm_mfma<4><<<dim3(6, 32), 256, 0, stream>>>(h1_bf, f2_bf, ffb2, core, 4096, DM, 928, DM,
                                                  nullptr, nullptr, nullptr, nullptr);
    ln_kernel<false><<<4096, 256, 0, stream>>>(out1f, core, ln2g, ln2b, out, nullptr);
}

// Round 13
// 387.333 us; speedup vs baseline: 2.2098x; 1.0390x over previous
//
#include <hip/hip_runtime.h>
#include <math.h>

#define QLEN 1024
#define BSZ 4
#define NH 10
#define DH 38
#define DM 380
#define DI 900
#define H3 1140
#define RLEN 2049
#define RLP 2112                      // RLEN padded to 33*64
#define SCALE 0.16222142113076254f   // 1/sqrt(38)

typedef unsigned short ushortt;
typedef __attribute__((ext_vector_type(8))) short short8;
typedef __attribute__((ext_vector_type(4))) float float4v;

__device__ __forceinline__ float bf2f(ushortt u) {
    return __uint_as_float(((unsigned int)u) << 16);
}
__device__ __forceinline__ ushortt f2bf(float f) {
    unsigned int u = __float_as_uint(f);
    u += 0x7fffu + ((u >> 16) & 1u);   // RNE
    return (ushortt)(u >> 16);
}

__device__ __forceinline__ void convseg(const float* src, ushortt* dst,
                                        int R, int C, int Rp, int Cp,
                                        int tid0, int stride) {
    const int total = Rp * Cp;
    for (int i = tid0; i < total; i += stride) {
        int r = i / Cp, c = i - r * Cp;
        float v = (r < R && c < C) ? src[(size_t)r * C + c] : 0.f;
        dst[i] = f2bf(v);
    }
}

// ---------- one fused prologue: all conversions + all pad zeroing ----------
__global__ __launch_bounds__(256)
void prep_all(const float* __restrict__ w,    ushortt* __restrict__ w_bf,
              const float* __restrict__ qkv,  ushortt* __restrict__ qkv_bf,
              const float* __restrict__ r,    ushortt* __restrict__ r_bf,
              const float* __restrict__ rw,   ushortt* __restrict__ rw_bf,
              const float* __restrict__ ow,   ushortt* __restrict__ ow_bf,
              const float* __restrict__ f1,   ushortt* __restrict__ f1_bf,
              const float* __restrict__ f2,   ushortt* __restrict__ f2_bf,
              float* __restrict__ qwp, ushortt* __restrict__ Kb, ushortt* __restrict__ Vb,
              ushortt* __restrict__ qr_bf, ushortt* __restrict__ rk_bf,
              ushortt* __restrict__ vec) {
    const int stride = gridDim.x * 256;
    const int tid0 = blockIdx.x * 256 + threadIdx.x;
    convseg(w,   w_bf,   4096, DM, 4096, 384, tid0, stride);
    convseg(qkv, qkv_bf, H3,   DM, 1152, 384, tid0, stride);
    convseg(r,   r_bf,   RLEN, DM, 2176, 384, tid0, stride);
    convseg(rw,  rw_bf,  DM,   DM, 384,  384, tid0, stride);
    convseg(ow,  ow_bf,  DM,   DM, 384,  384, tid0, stride);
    convseg(f1,  f1_bf,  DI,   DM, 960,  384, tid0, stride);
    convseg(f2,  f2_bf,  DM,   DI, 384,  928, tid0, stride);
    for (int i = tid0; i < BSZ * NH * 1024 * 2; i += stride) {     // d=38,39 pads
        size_t idx = (size_t)(i >> 1) * 40 + 38 + (i & 1);
        qwp[idx] = 0.f; Kb[idx] = 0; Vb[idx] = 0;
    }
    for (int i = tid0; i < 4096 * 4; i += stride)                  // vec cols 380..383
        vec[(size_t)(i >> 2) * 384 + 380 + (i & 3)] = 0;
    for (int i = tid0; i < BSZ * NH * 1024 * 26; i += stride) {    // qr cols 38..63
        int row = i / 26, c = 38 + i % 26;
        qr_bf[(size_t)row * 64 + c] = 0;
    }
    for (int i = tid0; i < NH * RLP * 26; i += stride) {           // rk cols 38..63
        int row = i / 26, c = 38 + i % 26;
        rk_bf[(size_t)row * 64 + c] = 0;
    }
    for (int i = tid0; i < NH * 63 * 64; i += stride) {            // rk rows 2049..2111
        int n = i / (63 * 64), rem = i % (63 * 64);
        rk_bf[((size_t)n * RLP + RLEN + rem / 64) * 64 + rem % 64] = 0;
    }
}

// ---------------- bf16 MFMA GEMM:  C[M,N] = A[M,Kp] * B[N,Kp]^T ----------------
// EPI: 0 = f32 store, 3 = relu(x+bias)->bf16 (ld 928), 4 = x+bias->f32,
//      5 = QKV scatter (qwp f32 + qr_bf bf16[64] + K_bf/V_bf bf16[40]),
//      6 = rk -> rk_bf bf16 [n][2112][64]
template<int EPI>
__global__ __launch_bounds__(256)
void gemm_mfma(const ushortt* __restrict__ A, const ushortt* __restrict__ B,
               const float* __restrict__ bias, void* __restrict__ Cout,
               int M, int N, int Kpp, int ldc,
               const float* __restrict__ bias2, float* __restrict__ out2,
               float* __restrict__ out3, float* __restrict__ out4) {
    __shared__ __align__(16) ushortt As[128 * 32];
    __shared__ __align__(16) ushortt Bs[64 * 32];
    const int tid = threadIdx.x;
    const int wid = tid >> 6, lane = tid & 63;
    const int bRow = blockIdx.y * 128, bCol = blockIdx.x * 64;

    float4v acc[2][4];
    const float4v zz = {0.f, 0.f, 0.f, 0.f};
    #pragma unroll
    for (int m = 0; m < 2; ++m)
        #pragma unroll
        for (int n = 0; n < 4; ++n) acc[m][n] = zz;

    const int arow = tid >> 1, acol = (tid & 1) * 16;
    const int brow = tid >> 2, bcol = (tid & 3) * 8;
    const int fr = lane & 15, kg = lane >> 4;

    for (int k0 = 0; k0 < Kpp; k0 += 32) {
        const ushortt* ag = A + (size_t)(bRow + arow) * Kpp + k0 + acol;
        float4v a0 = *(const float4v*)ag;
        float4v a1 = *(const float4v*)(ag + 8);
        const ushortt* bg = B + (size_t)(bCol + brow) * Kpp + k0 + bcol;
        float4v b0 = *(const float4v*)bg;
        __syncthreads();
        *(float4v*)&As[arow * 32 + acol] = a0;
        *(float4v*)&As[arow * 32 + acol + 8] = a1;
        *(float4v*)&Bs[brow * 32 + bcol] = b0;
        __syncthreads();

        short8 bf[4];
        #pragma unroll
        for (int n = 0; n < 4; ++n)
            bf[n] = *(const short8*)&Bs[(n * 16 + fr) * 32 + kg * 8];
        #pragma unroll
        for (int m = 0; m < 2; ++m) {
            short8 af = *(const short8*)&As[(wid * 32 + m * 16 + fr) * 32 + kg * 8];
            #pragma unroll
            for (int n = 0; n < 4; ++n)
                acc[m][n] = __builtin_amdgcn_mfma_f32_16x16x32_bf16(af, bf[n], acc[m][n], 0, 0, 0);
        }
    }

    #pragma unroll
    for (int m = 0; m < 2; ++m)
        #pragma unroll
        for (int n = 0; n < 4; ++n)
            #pragma unroll
            for (int j = 0; j < 4; ++j) {
                const int row = bRow + wid * 32 + m * 16 + (lane >> 4) * 4 + j;
                const int col = bCol + n * 16 + (lane & 15);
                const float v = acc[m][n][j];
                if (EPI == 0) {
                    if (row < M && col < N) ((float*)Cout)[(size_t)row * ldc + col] = v;
                } else if (EPI == 3) {
                    if (row < M && col < 928) {
                        float h = (col < DI) ? fmaxf(v + bias[col], 0.f) : 0.f;
                        ((ushortt*)Cout)[(size_t)row * 928 + col] = f2bf(h);
                    }
                } else if (EPI == 4) {
                    if (row < M && col < N) ((float*)Cout)[(size_t)row * ldc + col] = v + bias[col];
                } else if (EPI == 5) {
                    if (col < H3) {
                        int part = col / 380;
                        int c = col - part * 380;
                        int nh = c / 38, d = c - nh * 38;
                        int q = row >> 2, b2 = row & 3;
                        size_t idx = (((size_t)b2 * NH + nh) * 1024 + q) * 40 + d;
                        if (part == 0) {
                            ((float*)Cout)[idx] = v + bias[c];                 // qwp (+r_w_bias)
                            ((ushortt*)out2)[(((size_t)b2 * NH + nh) * 1024 + q) * 64 + d]
                                = f2bf(v + bias2[c]);                          // qr_bf (+r_r_bias)
                        } else if (part == 1) ((ushortt*)out3)[idx] = f2bf(v); // K_bf
                        else ((ushortt*)out4)[idx] = f2bf(v);                  // V_bf
                    }
                } else {  // EPI 6
                    if (row < RLEN && col < DM) {
                        int nh = col / 38, d = col - nh * 38;
                        ((ushortt*)Cout)[((size_t)nh * RLP + row) * 64 + d] = f2bf(v);
                    }
                }
            }
}

// ---------------- BD GEMM: all 10 heads per block, coalesced [q][j][n] store -----
__global__ __launch_bounds__(256)
void bd_gemm(const ushortt* __restrict__ qr, const ushortt* __restrict__ rk,
             ushortt* __restrict__ BD, int bofs) {
    __shared__ __align__(16) ushortt As[64][72];
    __shared__ __align__(16) ushortt Bs[32][72];
    __shared__ __align__(16) ushortt Call[64 * 32 * 10];
    const int tid = threadIdx.x;
    const int wid = tid >> 6, lane = tid & 63;
    const int jt = blockIdx.x, qt = blockIdx.y, lb = blockIdx.z;
    const int j0 = jt * 32, q0 = qt * 64;
    const int fr = lane & 15, kg = lane >> 4;
    const int jcount = min(32, RLEN - j0);

    for (int n = 0; n < NH; ++n) {
        const ushortt* Ab = qr + (((size_t)(bofs + lb) * NH + n) * 1024 + q0) * 64;
        const ushortt* Bb = rk + ((size_t)n * RLP + j0) * 64;
        __syncthreads();
        {
            int rr = tid >> 2, cc = (tid & 3) * 16;
            *(float4v*)&As[rr][cc] = *(const float4v*)(Ab + (size_t)rr * 64 + cc);
            *(float4v*)&As[rr][cc + 8] = *(const float4v*)(Ab + (size_t)rr * 64 + cc + 8);
            int br = tid >> 3, bc = (tid & 7) * 8;
            *(float4v*)&Bs[br][bc] = *(const float4v*)(Bb + (size_t)br * 64 + bc);
        }
        __syncthreads();
        float4v acc[2] = {{0.f,0.f,0.f,0.f},{0.f,0.f,0.f,0.f}};
        #pragma unroll
        for (int ks = 0; ks < 64; ks += 32) {
            short8 af = *(const short8*)&As[wid * 16 + fr][ks + kg * 8];
            #pragma unroll
            for (int c = 0; c < 2; ++c) {
                short8 bfr = *(const short8*)&Bs[c * 16 + fr][ks + kg * 8];
                acc[c] = __builtin_amdgcn_mfma_f32_16x16x32_bf16(af, bfr, acc[c], 0, 0, 0);
            }
        }
        #pragma unroll
        for (int c = 0; c < 2; ++c)
            #pragma unroll
            for (int jj = 0; jj < 4; ++jj) {
                int rq = wid * 16 + (lane >> 4) * 4 + jj;
                int cj = c * 16 + (lane & 15);
                Call[(rq * 32 + cj) * 10 + n] = f2bf(acc[c][jj]);
            }
    }
    __syncthreads();
    const int rowdw = jcount * 5;
    const unsigned* Cdw = (const unsigned*)Call;
    unsigned* G = (unsigned*)BD;
    for (int idx = tid; idx < 64 * rowdw; idx += 256) {
        int rr = idx / rowdw, rem = idx - rr * rowdw;
        size_t gdw = ((((size_t)lb * 1024 + q0 + rr) * RLEN + j0) * 10) / 2 + rem;
        G[gdw] = Cdw[rr * 160 + rem];
    }
}

// ---------------- balanced split-K fused attention, 32 q-rows per block -------
// qwp f32 / K_bf,V_bf bf16: [b][n][1024][40]; BD: bf16 [lb][1024 q][2049 j][NH]
// Work item = (qc, b, s); split s takes tiles s, s+ns, s+2ns, ... (ns=(qc>>3)+1)
// -> per-block work equal within 1 tile. 1-D XCD-grouped grid: 10 head-members
// per (qc,b,s) group land on ONE XCD (share BD lines + relpos rows).
__global__ __launch_bounds__(256)
void attn5(const float* __restrict__ qwp, const ushortt* __restrict__ Kp,
           const ushortt* __restrict__ Vp, const ushortt* __restrict__ BD,
           const int* __restrict__ relpos,
           ushortt* __restrict__ op, float2* __restrict__ ml, int b0, int nb) {
    const int bid = blockIdx.x;
    const int xcd = bid & 7, t = bid >> 3;
    const int gl = t / 10, n = t - gl * 10;
    const int G = gl * 8 + xcd;                // 0 .. 80*nb-1, heavy-first
    int qc, lb, s;
    {
        const int c3 = 32 * nb, c2 = 24 * nb, c1 = 16 * nb;
        if (G < c3)                { qc = 31 - G / (4 * nb); int r2 = G % (4 * nb); lb = r2 >> 2; s = r2 & 3; }
        else if (G < c3 + c2)      { int l2 = G - c3; qc = 23 - l2 / (3 * nb); int r2 = l2 % (3 * nb); lb = r2 / 3; s = r2 % 3; }
        else if (G < c3 + c2 + c1) { int l2 = G - c3 - c2; qc = 15 - l2 / (2 * nb); int r2 = l2 % (2 * nb); lb = r2 >> 1; s = r2 & 1; }
        else                       { int l2 = G - c3 - c2 - c1; qc = 7 - l2 / nb; lb = l2 % nb; s = 0; }
    }
    const int ns = (qc >> 3) + 1;
    const int qbase = qc * 32;
    const int b = b0 + lb;
    const int tid = threadIdx.x;
    const int row = tid >> 3, kg = tid & 7;
    const int qi = qbase + row;
    const size_t bn = (size_t)b * NH + n;
    const size_t prow = ((size_t)s * (BSZ * NH) + bn) * 1024 + qi;

    const int ntiles = (qbase + 95) >> 6;

    __shared__ __align__(16) float KtL[64 * 40];
    __shared__ __align__(16) float VtL[64 * 40];
    __shared__ float pL[32 * 66];

    const ushortt* Kbase = Kp + bn * 1024 * 40;
    const ushortt* Vbase = Vp + bn * 1024 * 40;

    float4v qw[10];
    {
        const float4v* src = (const float4v*)(qwp + (bn * 1024 + qi) * 40);
        #pragma unroll
        for (int i = 0; i < 10; ++i) qw[i] = src[i];
    }
    float o[5] = {0.f, 0.f, 0.f, 0.f, 0.f};
    float mrun = -INFINITY, lrun = 0.f;
    const int* rp = relpos + ((size_t)b * QLEN + qi) * QLEN;
    const ushortt* bdrow = BD + (((size_t)lb * 1024 + qi) * RLEN) * NH + n;

    for (int kt = s; kt < ntiles; kt += ns) {
        const int k0 = kt * 64;
        __syncthreads();
        {
            const short8* ks = (const short8*)(Kbase + (size_t)k0 * 40);
            const short8* vs = (const short8*)(Vbase + (size_t)k0 * 40);
            for (int e = tid; e < 320; e += 256) {
                short8 kv = ks[e], vv = vs[e];
                float4v k0v, k1v, v0v, v1v;
                #pragma unroll
                for (int x = 0; x < 4; ++x) {
                    k0v[x] = bf2f((ushortt)kv[x]);     k1v[x] = bf2f((ushortt)kv[4 + x]);
                    v0v[x] = bf2f((ushortt)vv[x]);     v1v[x] = bf2f((ushortt)vv[4 + x]);
                }
                ((float4v*)KtL)[e * 2] = k0v; ((float4v*)KtL)[e * 2 + 1] = k1v;
                ((float4v*)VtL)[e * 2] = v0v; ((float4v*)VtL)[e * 2 + 1] = v1v;
            }
        }
        __syncthreads();

        int jv[8];
        #pragma unroll
        for (int ss = 0; ss < 8; ++ss) {
            const int kk = k0 + kg + ss * 8;
            int j = -1;
            if (kk <= qi) {
                int rpv = rp[kk];
                rpv = rpv < -1024 ? -1024 : (rpv > 1024 ? 1024 : rpv);
                j = 1024 - rpv;
            }
            jv[ss] = j;
        }
        float bdv[8];
        #pragma unroll
        for (int ss = 0; ss < 8; ++ss)
            bdv[ss] = (jv[ss] >= 0) ? bf2f(bdrow[(size_t)jv[ss] * NH]) : 0.f;

        float sarr[8];
        float pmax = -INFINITY;
        #pragma unroll
        for (int ss = 0; ss < 8; ++ss) {
            float sv = -INFINITY;
            if (jv[ss] >= 0) {
                const int k = kg + ss * 8;
                float acc1 = 0.f;
                const float4v* kt4 = (const float4v*)(KtL + k * 40);
                #pragma unroll
                for (int i = 0; i < 10; ++i) {
                    float4v kv = kt4[i];
                    acc1 += qw[i][0] * kv[0] + qw[i][1] * kv[1]
                          + qw[i][2] * kv[2] + qw[i][3] * kv[3];
                }
                sv = (acc1 + bdv[ss]) * SCALE;
            }
            sarr[ss] = sv;
            pmax = fmaxf(pmax, sv);
        }
        pmax = fmaxf(pmax, __shfl_xor(pmax, 1, 64));
        pmax = fmaxf(pmax, __shfl_xor(pmax, 2, 64));
        pmax = fmaxf(pmax, __shfl_xor(pmax, 4, 64));
        const float nm = fmaxf(mrun, pmax);
        const float corr = __expf(mrun - nm);   // first tile: exp(-inf)=0
        float psum = 0.f;
        float* prw = pL + row * 66;
        #pragma unroll
        for (int ss = 0; ss < 8; ++ss) {
            float p = __expf(sarr[ss] - nm);
            psum += p;
            prw[kg + ss * 8] = p;
        }
        psum += __shfl_xor(psum, 1, 64);
        psum += __shfl_xor(psum, 2, 64);
        psum += __shfl_xor(psum, 4, 64);
        lrun = lrun * corr + psum;
        mrun = nm;
        #pragma unroll
        for (int jj = 0; jj < 5; ++jj) o[jj] *= corr;
        int kmax = qi - k0 + 1; if (kmax > 64) kmax = 64;
        #pragma unroll 4
        for (int k = 0; k < kmax; ++k) {
            float p = prw[k];
            const float* vr = VtL + k * 40;
            float4v v4 = *(const float4v*)(vr + 4 * kg);
            float v1 = vr[32 + kg];
            o[0] += p * v4[0]; o[1] += p * v4[1];
            o[2] += p * v4[2]; o[3] += p * v4[3];
            o[4] += p * v1;
        }
    }
    ushortt* oprow = op + prow * 40;
    #pragma unroll
    for (int jj = 0; jj < 4; ++jj) oprow[4 * kg + jj] = f2bf(o[jj]);
    oprow[32 + kg] = f2bf(o[4]);
    if (kg == 0) ml[prow] = make_float2(mrun, lrun);
}

// ---------------- combine split partials -> vec (bf16) ----------------
__global__ __launch_bounds__(256)
void attn_combine(const ushortt* __restrict__ op, const float2* __restrict__ ml,
                  ushortt* __restrict__ vec) {
    const int idx = blockIdx.x * 256 + threadIdx.x;
    if (idx >= BSZ * NH * 1024 * 38) return;
    const int d = idx % 38;
    const int rh = idx / 38;                 // bn*1024 + q
    const int q = rh & 1023;
    const int bn = rh >> 10;
    const int b = bn / NH, n = bn - b * NH;
    const int ns = ((q >> 5) >> 3) + 1;      // splits for this q's chunk
    const size_t stride = (size_t)BSZ * NH * 1024;
    float M = -INFINITY;
    float2 mv[4];
    for (int sp = 0; sp < ns; ++sp) {
        mv[sp] = ml[sp * stride + rh];
        M = fmaxf(M, mv[sp].x);
    }
    float l = 0.f, o = 0.f;
    for (int sp = 0; sp < ns; ++sp) {
        float w = __expf(mv[sp].x - M);
        l += mv[sp].y * w;
        o += bf2f(op[(sp * stride + rh) * 40 + d]) * w;
    }
    vec[((size_t)q * BSZ + b) * 384 + (size_t)n * 38 + d] = f2bf(o / l);
}

// ---------------- residual + LayerNorm ----------------
template<bool WRITE_BF>
__global__ __launch_bounds__(256)
void ln_kernel(const float* __restrict__ x1, const float* __restrict__ x2,
               const float* __restrict__ g, const float* __restrict__ bb,
               float* __restrict__ outf, ushortt* __restrict__ outbf) {
    const int row = blockIdx.x;
    const float* p1 = x1 + (size_t)row * DM;
    const float* p2 = x2 + (size_t)row * DM;
    __shared__ float xb[DM];
    __shared__ float red[256];
    const int tid = threadIdx.x;
    float s = 0.f;
    for (int i = tid; i < DM; i += 256) { float v = p1[i] + p2[i]; xb[i] = v; s += v; }
    red[tid] = s; __syncthreads();
    for (int st = 128; st > 0; st >>= 1) { if (tid < st) red[tid] += red[tid + st]; __syncthreads(); }
    const float mean = red[0] / DM;
    __syncthreads();
    float s2 = 0.f;
    for (int i = tid; i < DM; i += 256) { float d = xb[i] - mean; s2 += d * d; }
    red[tid] = s2; __syncthreads();
    for (int st = 128; st > 0; st >>= 1) { if (tid < st) red[tid] += red[tid + st]; __syncthreads(); }
    const float rstd = rsqrtf(red[0] / DM + 1e-5f);
    for (int i = tid; i < (WRITE_BF ? 384 : DM); i += 256) {
        float v = 0.f;
        if (i < DM) {
            v = (xb[i] - mean) * rstd * g[i] + bb[i];
            outf[(size_t)row * DM + i] = v;
        }
        if (WRITE_BF) outbf[(size_t)row * 384 + i] = f2bf(i < DM ? v : 0.f);
    }
}

extern "C" void kernel_launch(void* const* d_in, const int* in_sizes, int n_in,
                              void* d_out, int out_size, void* d_ws, size_t ws_size,
                              hipStream_t stream) {
    const float* w     = (const float*)d_in[0];
    const float* r     = (const float*)d_in[1];
    const float* rwb   = (const float*)d_in[2];
    const float* rrb   = (const float*)d_in[3];
    const float* qkv_w = (const float*)d_in[4];
    const float* r_w   = (const float*)d_in[5];
    const float* o_w   = (const float*)d_in[6];
    const float* ln1g  = (const float*)d_in[7];
    const float* ln1b  = (const float*)d_in[8];
    const float* ffw1  = (const float*)d_in[9];
    const float* ffb1  = (const float*)d_in[10];
    const float* ffw2  = (const float*)d_in[11];
    const float* ffb2  = (const float*)d_in[12];
    const float* ln2g  = (const float*)d_in[13];
    const float* ln2b  = (const float*)d_in[14];
    const int*   relpos = (const int*)d_in[16];
    float* out = (float*)d_out;

    char* cur = (char*)d_ws;
    auto alloc = [&](size_t bytes) { char* p = cur; cur += (bytes + 255) & ~(size_t)255; return p; };
    ushortt* w_bf    = (ushortt*)alloc((size_t)4096 * 384 * 2);
    ushortt* qkv_bf  = (ushortt*)alloc((size_t)1152 * 384 * 2);
    ushortt* r_bf    = (ushortt*)alloc((size_t)2176 * 384 * 2);
    ushortt* rw_bf   = (ushortt*)alloc((size_t)384 * 384 * 2);
    ushortt* ow_bf   = (ushortt*)alloc((size_t)384 * 384 * 2);
    ushortt* f1_bf   = (ushortt*)alloc((size_t)960 * 384 * 2);
    ushortt* f2_bf   = (ushortt*)alloc((size_t)384 * 928 * 2);
    float*   qwp     = (float*)alloc((size_t)BSZ * NH * 1024 * 40 * 4);
    ushortt* K_bf    = (ushortt*)alloc((size_t)BSZ * NH * 1024 * 40 * 2);
    ushortt* V_bf    = (ushortt*)alloc((size_t)BSZ * NH * 1024 * 40 * 2);
    ushortt* qr_bf   = (ushortt*)alloc((size_t)BSZ * NH * 1024 * 64 * 2);
    ushortt* rk_bf   = (ushortt*)alloc((size_t)NH * RLP * 64 * 2);
    ushortt* vec_bf  = (ushortt*)alloc((size_t)4096 * 384 * 2);
    ushortt* out1_bf = (ushortt*)alloc((size_t)4096 * 384 * 2);
    ushortt* h1_bf   = (ushortt*)alloc((size_t)4096 * 928 * 2);
    float*   attnf   = (float*)alloc((size_t)4096 * DM * 4);
    float*   out1f   = (float*)alloc((size_t)4096 * DM * 4);
    float*   core    = (float*)alloc((size_t)4096 * DM * 4);

    // split partials alias attnf/out1f/core (dead until after combine):
    ushortt* op_part = (ushortt*)attnf;
    float2*  ml_part = (float2*)((char*)attnf + (size_t)4 * BSZ * NH * 1024 * 40 * 2);

    // BD buffer: bf16 [lb][1024 q][2049 j][NH]
    const size_t bd_b_bytes = (size_t)1024 * RLEN * NH * 2;   // per-b: ~41 MB
    ushortt* BD = (ushortt*)alloc(bd_b_bytes * BSZ);
    bool full = ((size_t)(cur - (char*)d_ws) <= ws_size);
    if (!full) { cur = (char*)BD; BD = (ushortt*)alloc(bd_b_bytes); }  // per-b reuse

    auto cgrid = [](size_t total) { return dim3((unsigned)((total + 255) / 256)); };
    // fused prologue: all conversions + all pad zeroing, one launch
    prep_all<<<dim3(2048), 256, 0, stream>>>(w, w_bf, qkv_w, qkv_bf, r, r_bf,
                                             r_w, rw_bf, o_w, ow_bf, ffw1, f1_bf, ffw2, f2_bf,
                                             qwp, K_bf, V_bf, qr_bf, rk_bf, vec_bf);

    // QKV GEMM with scatter epilogue -> qwp / qr_bf / K_bf / V_bf
    gemm_mfma<5><<<dim3(18, 32), 256, 0, stream>>>(w_bf, qkv_bf, rwb, qwp, 4096, H3, 384, 0,
                                                   rrb, (float*)qr_bf, (float*)K_bf, (float*)V_bf);
    // rk GEMM -> rk_bf  bf16 [n][2112][64]
    gemm_mfma<6><<<dim3(6, 17), 256, 0, stream>>>(r_bf, rw_bf, nullptr, rk_bf, RLEN, DM, 384, 0,
                                                  nullptr, nullptr, nullptr, nullptr);
    if (full) {
        bd_gemm<<<dim3(65, 16, BSZ), 256, 0, stream>>>(qr_bf, rk_bf, BD, 0);
        attn5<<<dim3(3200), 256, 0, stream>>>(qwp, K_bf, V_bf, BD, relpos,
                                              op_part, ml_part, 0, BSZ);
    } else {
        for (int b = 0; b < BSZ; ++b) {
            bd_gemm<<<dim3(65, 16, 1), 256, 0, stream>>>(qr_bf, rk_bf, BD, b);
            attn5<<<dim3(800), 256, 0, stream>>>(qwp, K_bf, V_bf, BD, relpos,
                                                 op_part, ml_part, b, 1);
        }
    }
    attn_combine<<<cgrid((size_t)BSZ * NH * 1024 * 38), 256, 0, stream>>>(op_part, ml_part, vec_bf);
    // attn_out = vec @ o_w^T   (overwrites op_part alias -- partials are dead)
    gemm_mfma<0><<<dim3(6, 32), 256, 0, stream>>>(vec_bf, ow_bf, nullptr, attnf, 4096, DM, 384, DM,
                                                  nullptr, nullptr, nullptr, nullptr);
    ln_kernel<true><<<4096, 256, 0, stream>>>(w, attnf, ln1g, ln1b, out1f, out1_bf);
    gemm_mfma<3><<<dim3(15, 32), 256, 0, stream>>>(out1_bf, f1_bf, ffb1, h1_bf, 4096, DI, 384, 928,
                                                   nullptr, nullptr, nullptr, nullptr);
    gemm_mfma<4><<<dim3(6, 32), 256, 0, stream>>>(h1_bf, f2_bf, ffb2, core, 4096, DM, 928, DM,
                                                  nullptr, nullptr, nullptr, nullptr);
    ln_kernel<false><<<4096, 256, 0, stream>>>(out1f, core, ln2g, ln2b, out, nullptr);
}

// Round 14
// 378.659 us; speedup vs baseline: 2.2605x; 1.0229x over previous
//
#include <hip/hip_runtime.h>
#include <math.h>

#define QLEN 1024
#define BSZ 4
#define NH 10
#define DH 38
#define DM 380
#define DI 900
#define H3 1140
#define RLEN 2049
#define RLP 2112                      // RLEN padded to 33*64
#define SCALE 0.16222142113076254f   // 1/sqrt(38)

typedef unsigned short ushortt;
typedef __attribute__((ext_vector_type(8))) short short8;
typedef __attribute__((ext_vector_type(4))) float float4v;

__device__ __forceinline__ float bf2f(ushortt u) {
    return __uint_as_float(((unsigned int)u) << 16);
}
__device__ __forceinline__ ushortt f2bf(float f) {
    unsigned int u = __float_as_uint(f);
    u += 0x7fffu + ((u >> 16) & 1u);   // RNE
    return (ushortt)(u >> 16);
}

__device__ __forceinline__ void convseg(const float* src, ushortt* dst,
                                        int R, int C, int Rp, int Cp,
                                        int tid0, int stride) {
    const int total = Rp * Cp;
    for (int i = tid0; i < total; i += stride) {
        int r = i / Cp, c = i - r * Cp;
        float v = (r < R && c < C) ? src[(size_t)r * C + c] : 0.f;
        dst[i] = f2bf(v);
    }
}

// ---------- one fused prologue: all conversions + all pad zeroing ----------
__global__ __launch_bounds__(256)
void prep_all(const float* __restrict__ w,    ushortt* __restrict__ w_bf,
              const float* __restrict__ qkv,  ushortt* __restrict__ qkv_bf,
              const float* __restrict__ r,    ushortt* __restrict__ r_bf,
              const float* __restrict__ rw,   ushortt* __restrict__ rw_bf,
              const float* __restrict__ ow,   ushortt* __restrict__ ow_bf,
              const float* __restrict__ f1,   ushortt* __restrict__ f1_bf,
              const float* __restrict__ f2,   ushortt* __restrict__ f2_bf,
              ushortt* __restrict__ qw_bf, ushortt* __restrict__ Kb, ushortt* __restrict__ Vb,
              ushortt* __restrict__ qr_bf, ushortt* __restrict__ rk_bf,
              ushortt* __restrict__ vec) {
    const int stride = gridDim.x * 256;
    const int tid0 = blockIdx.x * 256 + threadIdx.x;
    convseg(w,   w_bf,   4096, DM, 4096, 384, tid0, stride);
    convseg(qkv, qkv_bf, H3,   DM, 1152, 384, tid0, stride);
    convseg(r,   r_bf,   RLEN, DM, 2176, 384, tid0, stride);
    convseg(rw,  rw_bf,  DM,   DM, 384,  384, tid0, stride);
    convseg(ow,  ow_bf,  DM,   DM, 384,  384, tid0, stride);
    convseg(f1,  f1_bf,  DI,   DM, 960,  384, tid0, stride);
    convseg(f2,  f2_bf,  DM,   DI, 384,  928, tid0, stride);
    for (int i = tid0; i < BSZ * NH * 1024 * 2; i += stride) {     // d=38,39 pads (K/V)
        size_t idx = (size_t)(i >> 1) * 40 + 38 + (i & 1);
        Kb[idx] = 0; Vb[idx] = 0;
    }
    for (int i = tid0; i < 4096 * 4; i += stride)                  // vec cols 380..383
        vec[(size_t)(i >> 2) * 384 + 380 + (i & 3)] = 0;
    for (int i = tid0; i < BSZ * NH * 1024 * 26; i += stride) {    // qr/qw cols 38..63
        int row = i / 26, c = 38 + i % 26;
        qr_bf[(size_t)row * 64 + c] = 0;
        qw_bf[(size_t)row * 64 + c] = 0;
    }
    for (int i = tid0; i < NH * RLP * 26; i += stride) {           // rk cols 38..63
        int row = i / 26, c = 38 + i % 26;
        rk_bf[(size_t)row * 64 + c] = 0;
    }
    for (int i = tid0; i < NH * 63 * 64; i += stride) {            // rk rows 2049..2111
        int n = i / (63 * 64), rem = i % (63 * 64);
        rk_bf[((size_t)n * RLP + RLEN + rem / 64) * 64 + rem % 64] = 0;
    }
}

// ---------------- bf16 MFMA GEMM:  C[M,N] = A[M,Kp] * B[N,Kp]^T ----------------
// EPI: 0 = f32 store, 3 = relu(x+bias)->bf16 (ld 928), 4 = x+bias->f32,
//      5 = QKV scatter (qw_bf/qr_bf bf16[64] + K_bf/V_bf bf16[40]),
//      6 = rk -> rk_bf bf16 [n][2112][64]
template<int EPI>
__global__ __launch_bounds__(256)
void gemm_mfma(const ushortt* __restrict__ A, const ushortt* __restrict__ B,
               const float* __restrict__ bias, void* __restrict__ Cout,
               int M, int N, int Kpp, int ldc,
               const float* __restrict__ bias2, float* __restrict__ out2,
               float* __restrict__ out3, float* __restrict__ out4) {
    __shared__ __align__(16) ushortt As[128 * 32];
    __shared__ __align__(16) ushortt Bs[64 * 32];
    const int tid = threadIdx.x;
    const int wid = tid >> 6, lane = tid & 63;
    const int bRow = blockIdx.y * 128, bCol = blockIdx.x * 64;

    float4v acc[2][4];
    const float4v zz = {0.f, 0.f, 0.f, 0.f};
    #pragma unroll
    for (int m = 0; m < 2; ++m)
        #pragma unroll
        for (int n = 0; n < 4; ++n) acc[m][n] = zz;

    const int arow = tid >> 1, acol = (tid & 1) * 16;
    const int brow = tid >> 2, bcol = (tid & 3) * 8;
    const int fr = lane & 15, kg = lane >> 4;

    for (int k0 = 0; k0 < Kpp; k0 += 32) {
        const ushortt* ag = A + (size_t)(bRow + arow) * Kpp + k0 + acol;
        float4v a0 = *(const float4v*)ag;
        float4v a1 = *(const float4v*)(ag + 8);
        const ushortt* bg = B + (size_t)(bCol + brow) * Kpp + k0 + bcol;
        float4v b0 = *(const float4v*)bg;
        __syncthreads();
        *(float4v*)&As[arow * 32 + acol] = a0;
        *(float4v*)&As[arow * 32 + acol + 8] = a1;
        *(float4v*)&Bs[brow * 32 + bcol] = b0;
        __syncthreads();

        short8 bf[4];
        #pragma unroll
        for (int n = 0; n < 4; ++n)
            bf[n] = *(const short8*)&Bs[(n * 16 + fr) * 32 + kg * 8];
        #pragma unroll
        for (int m = 0; m < 2; ++m) {
            short8 af = *(const short8*)&As[(wid * 32 + m * 16 + fr) * 32 + kg * 8];
            #pragma unroll
            for (int n = 0; n < 4; ++n)
                acc[m][n] = __builtin_amdgcn_mfma_f32_16x16x32_bf16(af, bf[n], acc[m][n], 0, 0, 0);
        }
    }

    #pragma unroll
    for (int m = 0; m < 2; ++m)
        #pragma unroll
        for (int n = 0; n < 4; ++n)
            #pragma unroll
            for (int j = 0; j < 4; ++j) {
                const int row = bRow + wid * 32 + m * 16 + (lane >> 4) * 4 + j;
                const int col = bCol + n * 16 + (lane & 15);
                const float v = acc[m][n][j];
                if (EPI == 0) {
                    if (row < M && col < N) ((float*)Cout)[(size_t)row * ldc + col] = v;
                } else if (EPI == 3) {
                    if (row < M && col < 928) {
                        float h = (col < DI) ? fmaxf(v + bias[col], 0.f) : 0.f;
                        ((ushortt*)Cout)[(size_t)row * 928 + col] = f2bf(h);
                    }
                } else if (EPI == 4) {
                    if (row < M && col < N) ((float*)Cout)[(size_t)row * ldc + col] = v + bias[col];
                } else if (EPI == 5) {
                    if (col < H3) {
                        int part = col / 380;
                        int c = col - part * 380;
                        int nh = c / 38, d = c - nh * 38;
                        int q = row >> 2, b2 = row & 3;
                        size_t i40 = (((size_t)b2 * NH + nh) * 1024 + q) * 40 + d;
                        size_t i64 = (((size_t)b2 * NH + nh) * 1024 + q) * 64 + d;
                        if (part == 0) {
                            ((ushortt*)Cout)[i64] = f2bf(v + bias[c]);         // qw_bf (+r_w_bias)
                            ((ushortt*)out2)[i64] = f2bf(v + bias2[c]);        // qr_bf (+r_r_bias)
                        } else if (part == 1) ((ushortt*)out3)[i40] = f2bf(v); // K_bf
                        else ((ushortt*)out4)[i40] = f2bf(v);                  // V_bf
                    }
                } else {  // EPI 6
                    if (row < RLEN && col < DM) {
                        int nh = col / 38, d = col - nh * 38;
                        ((ushortt*)Cout)[((size_t)nh * RLP + row) * 64 + d] = f2bf(v);
                    }
                }
            }
}

// ---------------- BD GEMM: all 10 heads per block, coalesced [q][j][n] store -----
// 1-D XCD-grouped grid: 65 jt-members per (lb,qt) group share the 80KB A-panel
// in one XCD's L2. grid = 65 * 16 * nb.
__global__ __launch_bounds__(256)
void bd_gemm(const ushortt* __restrict__ qr, const ushortt* __restrict__ rk,
             ushortt* __restrict__ BD, int bofs, int nb) {
    __shared__ __align__(16) ushortt As[64][72];
    __shared__ __align__(16) ushortt Bs[32][72];
    __shared__ __align__(16) ushortt Call[64 * 32 * 10];
    const int bid = blockIdx.x;
    const int xcd = bid & 7, t = bid >> 3;
    const int gl = t / 65, jt = t - gl * 65;
    const int G = gl * 8 + xcd;             // 0 .. 16*nb-1
    const int lb = G >> 4, qt = G & 15;
    const int tid = threadIdx.x;
    const int wid = tid >> 6, lane = tid & 63;
    const int j0 = jt * 32, q0 = qt * 64;
    const int fr = lane & 15, kg = lane >> 4;
    const int jcount = min(32, RLEN - j0);

    for (int n = 0; n < NH; ++n) {
        const ushortt* Ab = qr + (((size_t)(bofs + lb) * NH + n) * 1024 + q0) * 64;
        const ushortt* Bb = rk + ((size_t)n * RLP + j0) * 64;
        __syncthreads();
        {
            int rr = tid >> 2, cc = (tid & 3) * 16;
            *(float4v*)&As[rr][cc] = *(const float4v*)(Ab + (size_t)rr * 64 + cc);
            *(float4v*)&As[rr][cc + 8] = *(const float4v*)(Ab + (size_t)rr * 64 + cc + 8);
            int br = tid >> 3, bc = (tid & 7) * 8;
            *(float4v*)&Bs[br][bc] = *(const float4v*)(Bb + (size_t)br * 64 + bc);
        }
        __syncthreads();
        float4v acc[2] = {{0.f,0.f,0.f,0.f},{0.f,0.f,0.f,0.f}};
        #pragma unroll
        for (int ks = 0; ks < 64; ks += 32) {
            short8 af = *(const short8*)&As[wid * 16 + fr][ks + kg * 8];
            #pragma unroll
            for (int c = 0; c < 2; ++c) {
                short8 bfr = *(const short8*)&Bs[c * 16 + fr][ks + kg * 8];
                acc[c] = __builtin_amdgcn_mfma_f32_16x16x32_bf16(af, bfr, acc[c], 0, 0, 0);
            }
        }
        #pragma unroll
        for (int c = 0; c < 2; ++c)
            #pragma unroll
            for (int jj = 0; jj < 4; ++jj) {
                int rq = wid * 16 + (lane >> 4) * 4 + jj;
                int cj = c * 16 + (lane & 15);
                Call[(rq * 32 + cj) * 10 + n] = f2bf(acc[c][jj]);
            }
    }
    __syncthreads();
    const int rowdw = jcount * 5;
    const unsigned* Cdw = (const unsigned*)Call;
    unsigned* G2 = (unsigned*)BD;
    for (int idx = tid; idx < 64 * rowdw; idx += 256) {
        int rr = idx / rowdw, rem = idx - rr * rowdw;
        size_t gdw = ((((size_t)lb * 1024 + q0 + rr) * RLEN + j0) * 10) / 2 + rem;
        G2[gdw] = Cdw[rr * 160 + rem];
    }
}

// ---------------- MFMA-AC split-K fused attention, 32 q-rows per block -------
// qw_bf/K_bf/V_bf bf16: [b][n][1024][{64,40,40}]; BD: bf16 [lb][1024 q][2049 j][NH]
// AC = qw @ K^T via MFMA into sL; softmax + BD gather + VALU PV as before.
__global__ __launch_bounds__(256)
void attn6(const ushortt* __restrict__ qwb, const ushortt* __restrict__ Kp,
           const ushortt* __restrict__ Vp, const ushortt* __restrict__ BD,
           const int* __restrict__ relpos,
           ushortt* __restrict__ op, float2* __restrict__ ml, int b0, int nb) {
    const int bid = blockIdx.x;
    const int xcd = bid & 7, t = bid >> 3;
    const int gl = t / 10, n = t - gl * 10;
    const int G = gl * 8 + xcd;                // 0 .. 80*nb-1, heavy-first
    int qc, lb, s;
    {
        const int c3 = 32 * nb, c2 = 24 * nb, c1 = 16 * nb;
        if (G < c3)                { qc = 31 - G / (4 * nb); int r2 = G % (4 * nb); lb = r2 >> 2; s = r2 & 3; }
        else if (G < c3 + c2)      { int l2 = G - c3; qc = 23 - l2 / (3 * nb); int r2 = l2 % (3 * nb); lb = r2 / 3; s = r2 % 3; }
        else if (G < c3 + c2 + c1) { int l2 = G - c3 - c2; qc = 15 - l2 / (2 * nb); int r2 = l2 % (2 * nb); lb = r2 >> 1; s = r2 & 1; }
        else                       { int l2 = G - c3 - c2 - c1; qc = 7 - l2 / nb; lb = l2 % nb; s = 0; }
    }
    const int ns = (qc >> 3) + 1;
    const int qbase = qc * 32;
    const int b = b0 + lb;
    const int tid = threadIdx.x;
    const int wid = tid >> 6, lane = tid & 63;
    const int row = tid >> 3, kg = tid & 7;
    const int qi = qbase + row;
    const size_t bn = (size_t)b * NH + n;
    const size_t prow = ((size_t)s * (BSZ * NH) + bn) * 1024 + qi;
    const int ntiles = (qbase + 95) >> 6;

    __shared__ __align__(16) ushortt KtL[64 * 72];   // bf16, 144B row stride (2-way free)
    __shared__ __align__(16) float   VtL[64 * 40];
    __shared__ __align__(16) ushortt qwL[32 * 72];
    __shared__ __align__(16) ushortt sL[32 * 66];    // AC then p, bf16

    const ushortt* Kbase = Kp + bn * 1024 * 40;
    const ushortt* Vbase = Vp + bn * 1024 * 40;
    const int fr = lane & 15;
    const int kg8 = (lane >> 4) * 8;

    // block-start: stage qwL (32 x 64 bf16) + zero KtL cols 40..63
    {
        int r = tid >> 3, c = (tid & 7) * 8;
        *(short8*)&qwL[r * 72 + c] = *(const short8*)(qwb + (bn * 1024 + qbase + r) * 64 + c);
        for (int i = tid; i < 64 * 24; i += 256) {
            int rr = i / 24, cc = 40 + i % 24;
            KtL[rr * 72 + cc] = 0;
        }
    }
    float o[5] = {0.f, 0.f, 0.f, 0.f, 0.f};
    float mrun = -INFINITY, lrun = 0.f;
    const int* rp = relpos + ((size_t)b * QLEN + qi) * QLEN;
    const ushortt* bdrow = BD + (((size_t)lb * 1024 + qi) * RLEN) * NH + n;

    for (int kt = s; kt < ntiles; kt += ns) {
        const int k0 = kt * 64;
        __syncthreads();
        // stage K (raw bf16, cols 0..39) + V (f32)
        for (int e = tid; e < 320; e += 256) {
            int rr = e / 5, cc = (e % 5) * 8;
            *(short8*)&KtL[rr * 72 + cc] = *(const short8*)(Kbase + (size_t)(k0 + rr) * 40 + cc);
        }
        {
            const short8* vs = (const short8*)(Vbase + (size_t)k0 * 40);
            for (int e = tid; e < 320; e += 256) {
                short8 vv = vs[e];
                float4v v0v, v1v;
                #pragma unroll
                for (int x = 0; x < 4; ++x) {
                    v0v[x] = bf2f((ushortt)vv[x]); v1v[x] = bf2f((ushortt)vv[4 + x]);
                }
                ((float4v*)VtL)[e * 2] = v0v; ((float4v*)VtL)[e * 2 + 1] = v1v;
            }
        }
        __syncthreads();

        // BD gather (issued early; consumed after MFMA barrier)
        int jv[8];
        #pragma unroll
        for (int ss = 0; ss < 8; ++ss) {
            const int kk = k0 + kg + ss * 8;
            int j = -1;
            if (kk <= qi) {
                int rpv = rp[kk];
                rpv = rpv < -1024 ? -1024 : (rpv > 1024 ? 1024 : rpv);
                j = 1024 - rpv;
            }
            jv[ss] = j;
        }
        float bdv[8];
        #pragma unroll
        for (int ss = 0; ss < 8; ++ss)
            bdv[ss] = (jv[ss] >= 0) ? bf2f(bdrow[(size_t)jv[ss] * NH]) : 0.f;

        // MFMA: AC[32][64] = qw @ K^T  (wave -> (mt, 2 ct tiles))
        {
            const int mt = wid >> 1, ctb = (wid & 1) * 2;
            short8 a0 = *(const short8*)&qwL[(mt * 16 + fr) * 72 + kg8];
            short8 a1 = *(const short8*)&qwL[(mt * 16 + fr) * 72 + 32 + kg8];
            #pragma unroll
            for (int c = 0; c < 2; ++c) {
                const int ct = ctb + c;
                short8 b0f = *(const short8*)&KtL[(ct * 16 + fr) * 72 + kg8];
                short8 b1f = *(const short8*)&KtL[(ct * 16 + fr) * 72 + 32 + kg8];
                float4v acc = {0.f, 0.f, 0.f, 0.f};
                acc = __builtin_amdgcn_mfma_f32_16x16x32_bf16(a0, b0f, acc, 0, 0, 0);
                acc = __builtin_amdgcn_mfma_f32_16x16x32_bf16(a1, b1f, acc, 0, 0, 0);
                #pragma unroll
                for (int j = 0; j < 4; ++j)
                    sL[(mt * 16 + (lane >> 4) * 4 + j) * 66 + ct * 16 + fr] = f2bf(acc[j]);
            }
        }
        __syncthreads();

        // score combine + online softmax (thread owns cells (row, kg+ss*8))
        float sarr[8];
        float pmax = -INFINITY;
        #pragma unroll
        for (int ss = 0; ss < 8; ++ss) {
            float sv = -INFINITY;
            if (jv[ss] >= 0)
                sv = (bf2f(sL[row * 66 + kg + ss * 8]) + bdv[ss]) * SCALE;
            sarr[ss] = sv;
            pmax = fmaxf(pmax, sv);
        }
        pmax = fmaxf(pmax, __shfl_xor(pmax, 1, 64));
        pmax = fmaxf(pmax, __shfl_xor(pmax, 2, 64));
        pmax = fmaxf(pmax, __shfl_xor(pmax, 4, 64));
        const float nm = fmaxf(mrun, pmax);
        const float corr = __expf(mrun - nm);   // first tile: exp(-inf)=0
        float psum = 0.f;
        ushortt* prw = sL + row * 66;
        #pragma unroll
        for (int ss = 0; ss < 8; ++ss) {
            float p = __expf(sarr[ss] - nm);
            psum += p;
            prw[kg + ss * 8] = f2bf(p);
        }
        psum += __shfl_xor(psum, 1, 64);
        psum += __shfl_xor(psum, 2, 64);
        psum += __shfl_xor(psum, 4, 64);
        lrun = lrun * corr + psum;
        mrun = nm;
        #pragma unroll
        for (int jj = 0; jj < 5; ++jj) o[jj] *= corr;
        int kmax = qi - k0 + 1; if (kmax > 64) kmax = 64;
        #pragma unroll 4
        for (int k = 0; k < kmax; ++k) {
            float p = bf2f(prw[k]);
            const float* vr = VtL + k * 40;
            float4v v4 = *(const float4v*)(vr + 4 * kg);
            float v1 = vr[32 + kg];
            o[0] += p * v4[0]; o[1] += p * v4[1];
            o[2] += p * v4[2]; o[3] += p * v4[3];
            o[4] += p * v1;
        }
    }
    ushortt* oprow = op + prow * 40;
    #pragma unroll
    for (int jj = 0; jj < 4; ++jj) oprow[4 * kg + jj] = f2bf(o[jj]);
    oprow[32 + kg] = f2bf(o[4]);
    if (kg == 0) ml[prow] = make_float2(mrun, lrun);
}

// ---------------- combine split partials -> vec (bf16) ----------------
__global__ __launch_bounds__(256)
void attn_combine(const ushortt* __restrict__ op, const float2* __restrict__ ml,
                  ushortt* __restrict__ vec) {
    const int idx = blockIdx.x * 256 + threadIdx.x;
    if (idx >= BSZ * NH * 1024 * 38) return;
    const int d = idx % 38;
    const int rh = idx / 38;                 // bn*1024 + q
    const int q = rh & 1023;
    const int bn = rh >> 10;
    const int b = bn / NH, n = bn - b * NH;
    const int ns = ((q >> 5) >> 3) + 1;      // splits for this q's chunk
    const size_t stride = (size_t)BSZ * NH * 1024;
    float M = -INFINITY;
    float2 mv[4];
    for (int sp = 0; sp < ns; ++sp) {
        mv[sp] = ml[sp * stride + rh];
        M = fmaxf(M, mv[sp].x);
    }
    float l = 0.f, o = 0.f;
    for (int sp = 0; sp < ns; ++sp) {
        float w = __expf(mv[sp].x - M);
        l += mv[sp].y * w;
        o += bf2f(op[(sp * stride + rh) * 40 + d]) * w;
    }
    vec[((size_t)q * BSZ + b) * 384 + (size_t)n * 38 + d] = f2bf(o / l);
}

// ---------------- residual + LayerNorm ----------------
template<bool WRITE_BF>
__global__ __launch_bounds__(256)
void ln_kernel(const float* __restrict__ x1, const float* __restrict__ x2,
               const float* __restrict__ g, const float* __restrict__ bb,
               float* __restrict__ outf, ushortt* __restrict__ outbf) {
    const int row = blockIdx.x;
    const float* p1 = x1 + (size_t)row * DM;
    const float* p2 = x2 + (size_t)row * DM;
    __shared__ float xb[DM];
    __shared__ float red[256];
    const int tid = threadIdx.x;
    float s = 0.f;
    for (int i = tid; i < DM; i += 256) { float v = p1[i] + p2[i]; xb[i] = v; s += v; }
    red[tid] = s; __syncthreads();
    for (int st = 128; st > 0; st >>= 1) { if (tid < st) red[tid] += red[tid + st]; __syncthreads(); }
    const float mean = red[0] / DM;
    __syncthreads();
    float s2 = 0.f;
    for (int i = tid; i < DM; i += 256) { float d = xb[i] - mean; s2 += d * d; }
    red[tid] = s2; __syncthreads();
    for (int st = 128; st > 0; st >>= 1) { if (tid < st) red[tid] += red[tid + st]; __syncthreads(); }
    const float rstd = rsqrtf(red[0] / DM + 1e-5f);
    for (int i = tid; i < (WRITE_BF ? 384 : DM); i += 256) {
        float v = 0.f;
        if (i < DM) {
            v = (xb[i] - mean) * rstd * g[i] + bb[i];
            outf[(size_t)row * DM + i] = v;
        }
        if (WRITE_BF) outbf[(size_t)row * 384 + i] = f2bf(i < DM ? v : 0.f);
    }
}

extern "C" void kernel_launch(void* const* d_in, const int* in_sizes, int n_in,
                              void* d_out, int out_size, void* d_ws, size_t ws_size,
                              hipStream_t stream) {
    const float* w     = (const float*)d_in[0];
    const float* r     = (const float*)d_in[1];
    const float* rwb   = (const float*)d_in[2];
    const float* rrb   = (const float*)d_in[3];
    const float* qkv_w = (const float*)d_in[4];
    const float* r_w   = (const float*)d_in[5];
    const float* o_w   = (const float*)d_in[6];
    const float* ln1g  = (const float*)d_in[7];
    const float* ln1b  = (const float*)d_in[8];
    const float* ffw1  = (const float*)d_in[9];
    const float* ffb1  = (const float*)d_in[10];
    const float* ffw2  = (const float*)d_in[11];
    const float* ffb2  = (const float*)d_in[12];
    const float* ln2g  = (const float*)d_in[13];
    const float* ln2b  = (const float*)d_in[14];
    const int*   relpos = (const int*)d_in[16];
    float* out = (float*)d_out;

    char* cur = (char*)d_ws;
    auto alloc = [&](size_t bytes) { char* p = cur; cur += (bytes + 255) & ~(size_t)255; return p; };
    ushortt* w_bf    = (ushortt*)alloc((size_t)4096 * 384 * 2);
    ushortt* qkv_bf  = (ushortt*)alloc((size_t)1152 * 384 * 2);
    ushortt* r_bf    = (ushortt*)alloc((size_t)2176 * 384 * 2);
    ushortt* rw_bf   = (ushortt*)alloc((size_t)384 * 384 * 2);
    ushortt* ow_bf   = (ushortt*)alloc((size_t)384 * 384 * 2);
    ushortt* f1_bf   = (ushortt*)alloc((size_t)960 * 384 * 2);
    ushortt* f2_bf   = (ushortt*)alloc((size_t)384 * 928 * 2);
    ushortt* qw_bf   = (ushortt*)alloc((size_t)BSZ * NH * 1024 * 64 * 2);
    ushortt* K_bf    = (ushortt*)alloc((size_t)BSZ * NH * 1024 * 40 * 2);
    ushortt* V_bf    = (ushortt*)alloc((size_t)BSZ * NH * 1024 * 40 * 2);
    ushortt* qr_bf   = (ushortt*)alloc((size_t)BSZ * NH * 1024 * 64 * 2);
    ushortt* rk_bf   = (ushortt*)alloc((size_t)NH * RLP * 64 * 2);
    ushortt* vec_bf  = (ushortt*)alloc((size_t)4096 * 384 * 2);
    ushortt* out1_bf = (ushortt*)alloc((size_t)4096 * 384 * 2);
    ushortt* h1_bf   = (ushortt*)alloc((size_t)4096 * 928 * 2);
    float*   attnf   = (float*)alloc((size_t)4096 * DM * 4);
    float*   out1f   = (float*)alloc((size_t)4096 * DM * 4);
    float*   core    = (float*)alloc((size_t)4096 * DM * 4);

    // split partials alias attnf/out1f/core (dead until after combine):
    ushortt* op_part = (ushortt*)attnf;
    float2*  ml_part = (float2*)((char*)attnf + (size_t)4 * BSZ * NH * 1024 * 40 * 2);

    // BD buffer: bf16 [lb][1024 q][2049 j][NH]
    const size_t bd_b_bytes = (size_t)1024 * RLEN * NH * 2;   // per-b: ~41 MB
    ushortt* BD = (ushortt*)alloc(bd_b_bytes * BSZ);
    bool full = ((size_t)(cur - (char*)d_ws) <= ws_size);
    if (!full) { cur = (char*)BD; BD = (ushortt*)alloc(bd_b_bytes); }  // per-b reuse

    auto cgrid = [](size_t total) { return dim3((unsigned)((total + 255) / 256)); };
    // fused prologue: all conversions + all pad zeroing, one launch
    prep_all<<<dim3(2048), 256, 0, stream>>>(w, w_bf, qkv_w, qkv_bf, r, r_bf,
                                             r_w, rw_bf, o_w, ow_bf, ffw1, f1_bf, ffw2, f2_bf,
                                             qw_bf, K_bf, V_bf, qr_bf, rk_bf, vec_bf);

    // QKV GEMM with scatter epilogue -> qw_bf / qr_bf / K_bf / V_bf
    gemm_mfma<5><<<dim3(18, 32), 256, 0, stream>>>(w_bf, qkv_bf, rwb, qw_bf, 4096, H3, 384, 0,
                                                   rrb, (float*)qr_bf, (float*)K_bf, (float*)V_bf);
    // rk GEMM -> rk_bf  bf16 [n][2112][64]
    gemm_mfma<6><<<dim3(6, 17), 256, 0, stream>>>(r_bf, rw_bf, nullptr, rk_bf, RLEN, DM, 384, 0,
                                                  nullptr, nullptr, nullptr, nullptr);
    if (full) {
        bd_gemm<<<dim3(65 * 16 * BSZ), 256, 0, stream>>>(qr_bf, rk_bf, BD, 0, BSZ);
        attn6<<<dim3(3200), 256, 0, stream>>>(qw_bf, K_bf, V_bf, BD, relpos,
                                              op_part, ml_part, 0, BSZ);
    } else {
        for (int b = 0; b < BSZ; ++b) {
            bd_gemm<<<dim3(65 * 16), 256, 0, stream>>>(qr_bf, rk_bf, BD, b, 1);
            attn6<<<dim3(800), 256, 0, stream>>>(qw_bf, K_bf, V_bf, BD, relpos,
                                                 op_part, ml_part, b, 1);
        }
    }
    attn_combine<<<cgrid((size_t)BSZ * NH * 1024 * 38), 256, 0, stream>>>(op_part, ml_part, vec_bf);
    // attn_out = vec @ o_w^T   (overwrites op_part alias -- partials are dead)
    gemm_mfma<0><<<dim3(6, 32), 256, 0, stream>>>(vec_bf, ow_bf, nullptr, attnf, 4096, DM, 384, DM,
                                                  nullptr, nullptr, nullptr, nullptr);
    ln_kernel<true><<<4096, 256, 0, stream>>>(w, attnf, ln1g, ln1b, out1f, out1_bf);
    gemm_mfma<3><<<dim3(15, 32), 256, 0, stream>>>(out1_bf, f1_bf, ffb1, h1_bf, 4096, DI, 384, 928,
                                                   nullptr, nullptr, nullptr, nullptr);
    gemm_mfma<4><<<dim3(6, 32), 256, 0, stream>>>(h1_bf, f2_bf, ffb2, core, 4096, DM, 928, DM,
                                                  nullptr, nullptr, nullptr, nullptr);
    ln_kernel<false><<<4096, 256, 0, stream>>>(out1f, core, ln2g, ln2b, out, nullptr);
}

// Round 16
// 352.364 us; speedup vs baseline: 2.4291x; 1.0746x over previous
//
#include <hip/hip_runtime.h>
#include <math.h>

#define QLEN 1024
#define BSZ 4
#define NH 10
#define DH 38
#define DM 380
#define DI 900
#define H3 1140
#define RLEN 2049
#define RLP 2112                      // RLEN padded to 33*64 (rk rows)
#define RLD 2052                      // BD row stride (10B entries, dword-aligned rows)
#define SCALE 0.16222142113076254f   // 1/sqrt(38)

typedef unsigned short ushortt;
typedef unsigned char uchar;
typedef __attribute__((ext_vector_type(8))) short short8;
typedef __attribute__((ext_vector_type(4))) float float4v;

__device__ __forceinline__ float bf2f(ushortt u) {
    return __uint_as_float(((unsigned int)u) << 16);
}
__device__ __forceinline__ ushortt f2bf(float f) {
    unsigned int u = __float_as_uint(f);
    u += 0x7fffu + ((u >> 16) & 1u);   // RNE
    return (ushortt)(u >> 16);
}
// ---- fp8 e4m3fn codec (flush subnormals; saturate to 448) ----
__device__ __forceinline__ uchar f2e4m3(float f) {
    unsigned u = __float_as_uint(f);
    unsigned s = (u >> 24) & 0x80u;
    unsigned b = u & 0x7fffffffu;
    b += 0x7FFFFu + ((b >> 20) & 1u);          // RNE to 3 mantissa bits
    int E = (int)(b >> 23) - 120;              // e4m3 exponent field
    if (E <= 0) return (uchar)s;               // underflow -> 0
    if (E > 15 || (E == 15 && ((b >> 20) & 7u) > 6u)) return (uchar)(s | 0x7Eu);
    return (uchar)(s | ((unsigned)E << 3) | ((b >> 20) & 7u));
}
__device__ __forceinline__ float e4m32f(uchar v) {
    unsigned s = ((unsigned)(v & 0x80u)) << 24;
    int E = (v >> 3) & 15; unsigned m = v & 7u;
    if (E == 0) return __uint_as_float(s);     // flush
    return __uint_as_float(s | ((unsigned)(E + 120) << 23) | (m << 20));
}

__device__ __forceinline__ void convseg(const float* src, ushortt* dst,
                                        int R, int C, int Rp, int Cp,
                                        int tid0, int stride) {
    const int total = Rp * Cp;
    for (int i = tid0; i < total; i += stride) {
        int r = i / Cp, c = i - r * Cp;
        float v = (r < R && c < C) ? src[(size_t)r * C + c] : 0.f;
        dst[i] = f2bf(v);
    }
}

// ---------- one fused prologue: all conversions + all pad zeroing ----------
__global__ __launch_bounds__(256)
void prep_all(const float* __restrict__ w,    ushortt* __restrict__ w_bf,
              const float* __restrict__ qkv,  ushortt* __restrict__ qkv_bf,
              const float* __restrict__ r,    ushortt* __restrict__ r_bf,
              const float* __restrict__ rw,   ushortt* __restrict__ rw_bf,
              const float* __restrict__ ow,   ushortt* __restrict__ ow_bf,
              const float* __restrict__ f1,   ushortt* __restrict__ f1_bf,
              const float* __restrict__ f2,   ushortt* __restrict__ f2_bf,
              ushortt* __restrict__ qw_bf, ushortt* __restrict__ Kb, ushortt* __restrict__ Vb,
              ushortt* __restrict__ qr_bf, ushortt* __restrict__ rk_bf,
              ushortt* __restrict__ vec) {
    const int stride = gridDim.x * 256;
    const int tid0 = blockIdx.x * 256 + threadIdx.x;
    convseg(w,   w_bf,   4096, DM, 4096, 384, tid0, stride);
    convseg(qkv, qkv_bf, H3,   DM, 1152, 384, tid0, stride);
    convseg(r,   r_bf,   RLEN, DM, 2176, 384, tid0, stride);
    convseg(rw,  rw_bf,  DM,   DM, 384,  384, tid0, stride);
    convseg(ow,  ow_bf,  DM,   DM, 384,  384, tid0, stride);
    convseg(f1,  f1_bf,  DI,   DM, 960,  384, tid0, stride);
    convseg(f2,  f2_bf,  DM,   DI, 384,  928, tid0, stride);
    for (int i = tid0; i < BSZ * NH * 1024 * 2; i += stride) {     // d=38,39 pads (qw/K/V)
        size_t idx = (size_t)(i >> 1) * 40 + 38 + (i & 1);
        qw_bf[idx] = 0; Kb[idx] = 0; Vb[idx] = 0;
    }
    for (int i = tid0; i < 4096 * 4; i += stride)                  // vec cols 380..383
        vec[(size_t)(i >> 2) * 384 + 380 + (i & 3)] = 0;
    for (int i = tid0; i < BSZ * NH * 1024 * 26; i += stride) {    // qr cols 38..63
        int row = i / 26, c = 38 + i % 26;
        qr_bf[(size_t)row * 64 + c] = 0;
    }
    for (int i = tid0; i < NH * RLP * 26; i += stride) {           // rk cols 38..63
        int row = i / 26, c = 38 + i % 26;
        rk_bf[(size_t)row * 64 + c] = 0;
    }
    for (int i = tid0; i < NH * 63 * 64; i += stride) {            // rk rows 2049..2111
        int n = i / (63 * 64), rem = i % (63 * 64);
        rk_bf[((size_t)n * RLP + RLEN + rem / 64) * 64 + rem % 64] = 0;
    }
}

// ---------------- bf16 MFMA GEMM:  C[M,N] = A[M,Kp] * B[N,Kp]^T ----------------
// EPI: 0 = f32 store, 3 = relu(x+bias)->bf16 (ld 928), 4 = x+bias->f32,
//      5 = QKV scatter (qw_bf bf16[40] + qr_bf bf16[64] + K_bf/V_bf bf16[40]),
//      6 = rk -> rk_bf bf16 [n][2112][64]
template<int EPI>
__global__ __launch_bounds__(256)
void gemm_mfma(const ushortt* __restrict__ A, const ushortt* __restrict__ B,
               const float* __restrict__ bias, void* __restrict__ Cout,
               int M, int N, int Kpp, int ldc,
               const float* __restrict__ bias2, float* __restrict__ out2,
               float* __restrict__ out3, float* __restrict__ out4) {
    __shared__ __align__(16) ushortt As[128 * 32];
    __shared__ __align__(16) ushortt Bs[64 * 32];
    const int tid = threadIdx.x;
    const int wid = tid >> 6, lane = tid & 63;
    const int bRow = blockIdx.y * 128, bCol = blockIdx.x * 64;

    float4v acc[2][4];
    const float4v zz = {0.f, 0.f, 0.f, 0.f};
    #pragma unroll
    for (int m = 0; m < 2; ++m)
        #pragma unroll
        for (int n = 0; n < 4; ++n) acc[m][n] = zz;

    const int arow = tid >> 1, acol = (tid & 1) * 16;
    const int brow = tid >> 2, bcol = (tid & 3) * 8;
    const int fr = lane & 15, kg = lane >> 4;

    for (int k0 = 0; k0 < Kpp; k0 += 32) {
        const ushortt* ag = A + (size_t)(bRow + arow) * Kpp + k0 + acol;
        float4v a0 = *(const float4v*)ag;
        float4v a1 = *(const float4v*)(ag + 8);
        const ushortt* bg = B + (size_t)(bCol + brow) * Kpp + k0 + bcol;
        float4v b0 = *(const float4v*)bg;
        __syncthreads();
        *(float4v*)&As[arow * 32 + acol] = a0;
        *(float4v*)&As[arow * 32 + acol + 8] = a1;
        *(float4v*)&Bs[brow * 32 + bcol] = b0;
        __syncthreads();

        short8 bf[4];
        #pragma unroll
        for (int n = 0; n < 4; ++n)
            bf[n] = *(const short8*)&Bs[(n * 16 + fr) * 32 + kg * 8];
        #pragma unroll
        for (int m = 0; m < 2; ++m) {
            short8 af = *(const short8*)&As[(wid * 32 + m * 16 + fr) * 32 + kg * 8];
            #pragma unroll
            for (int n = 0; n < 4; ++n)
                acc[m][n] = __builtin_amdgcn_mfma_f32_16x16x32_bf16(af, bf[n], acc[m][n], 0, 0, 0);
        }
    }

    #pragma unroll
    for (int m = 0; m < 2; ++m)
        #pragma unroll
        for (int n = 0; n < 4; ++n)
            #pragma unroll
            for (int j = 0; j < 4; ++j) {
                const int row = bRow + wid * 32 + m * 16 + (lane >> 4) * 4 + j;
                const int col = bCol + n * 16 + (lane & 15);
                const float v = acc[m][n][j];
                if (EPI == 0) {
                    if (row < M && col < N) ((float*)Cout)[(size_t)row * ldc + col] = v;
                } else if (EPI == 3) {
                    if (row < M && col < 928) {
                        float h = (col < DI) ? fmaxf(v + bias[col], 0.f) : 0.f;
                        ((ushortt*)Cout)[(size_t)row * 928 + col] = f2bf(h);
                    }
                } else if (EPI == 4) {
                    if (row < M && col < N) ((float*)Cout)[(size_t)row * ldc + col] = v + bias[col];
                } else if (EPI == 5) {
                    if (col < H3) {
                        int part = col / 380;
                        int c = col - part * 380;
                        int nh = c / 38, d = c - nh * 38;
                        int q = row >> 2, b2 = row & 3;
                        size_t i40 = (((size_t)b2 * NH + nh) * 1024 + q) * 40 + d;
                        size_t i64 = (((size_t)b2 * NH + nh) * 1024 + q) * 64 + d;
                        if (part == 0) {
                            ((ushortt*)Cout)[i40] = f2bf(v + bias[c]);         // qw_bf (+r_w_bias)
                            ((ushortt*)out2)[i64] = f2bf(v + bias2[c]);        // qr_bf (+r_r_bias)
                        } else if (part == 1) ((ushortt*)out3)[i40] = f2bf(v); // K_bf
                        else ((ushortt*)out4)[i40] = f2bf(v);                  // V_bf
                    }
                } else {  // EPI 6
                    if (row < RLEN && col < DM) {
                        int nh = col / 38, d = col - nh * 38;
                        ((ushortt*)Cout)[((size_t)nh * RLP + row) * 64 + d] = f2bf(v);
                    }
                }
            }
}

// ---------------- BD GEMM: all 10 heads per block, fp8 out, coalesced store -----
// BD: fp8 [lb][1024 q][2052 j][10 n]; 1-D XCD-grouped grid (65 jt share A-panel).
__global__ __launch_bounds__(256)
void bd_gemm(const ushortt* __restrict__ qr, const ushortt* __restrict__ rk,
             uchar* __restrict__ BD, int bofs, int nb) {
    __shared__ __align__(16) ushortt As[64][72];
    __shared__ __align__(16) ushortt Bs[32][72];
    __shared__ __align__(16) uchar Call[64 * 32 * 10];
    const int bid = blockIdx.x;
    const int xcd = bid & 7, t = bid >> 3;
    const int gl = t / 65, jt = t - gl * 65;
    const int G = gl * 8 + xcd;             // 0 .. 16*nb-1
    const int lb = G >> 4, qt = G & 15;
    const int tid = threadIdx.x;
    const int wid = tid >> 6, lane = tid & 63;
    const int j0 = jt * 32, q0 = qt * 64;
    const int fr = lane & 15, kg = lane >> 4;
    const int jcount = min(32, RLEN - j0);

    for (int n = 0; n < NH; ++n) {
        const ushortt* Ab = qr + (((size_t)(bofs + lb) * NH + n) * 1024 + q0) * 64;
        const ushortt* Bb = rk + ((size_t)n * RLP + j0) * 64;
        __syncthreads();
        {
            int rr = tid >> 2, cc = (tid & 3) * 16;
            *(float4v*)&As[rr][cc] = *(const float4v*)(Ab + (size_t)rr * 64 + cc);
            *(float4v*)&As[rr][cc + 8] = *(const float4v*)(Ab + (size_t)rr * 64 + cc + 8);
            int br = tid >> 3, bc = (tid & 7) * 8;
            *(float4v*)&Bs[br][bc] = *(const float4v*)(Bb + (size_t)br * 64 + bc);
        }
        __syncthreads();
        float4v acc[2] = {{0.f,0.f,0.f,0.f},{0.f,0.f,0.f,0.f}};
        #pragma unroll
        for (int ks = 0; ks < 64; ks += 32) {
            short8 af = *(const short8*)&As[wid * 16 + fr][ks + kg * 8];
            #pragma unroll
            for (int c = 0; c < 2; ++c) {
                short8 bfr = *(const short8*)&Bs[c * 16 + fr][ks + kg * 8];
                acc[c] = __builtin_amdgcn_mfma_f32_16x16x32_bf16(af, bfr, acc[c], 0, 0, 0);
            }
        }
        #pragma unroll
        for (int c = 0; c < 2; ++c)
            #pragma unroll
            for (int jj = 0; jj < 4; ++jj) {
                int rq = wid * 16 + (lane >> 4) * 4 + jj;
                int cj = c * 16 + (lane & 15);
                Call[(rq * 32 + cj) * 10 + n] = f2e4m3(acc[c][jj]);
            }
    }
    __syncthreads();
    if (jcount == 32) {
        const unsigned* Cdw = (const unsigned*)Call;
        unsigned* G2 = (unsigned*)BD;
        for (int idx = tid; idx < 64 * 80; idx += 256) {
            int rr = idx / 80, rem = idx - rr * 80;
            size_t gdw = (((size_t)(lb * 1024 + q0 + rr) * RLD + j0) * 10) >> 2;
            G2[gdw + rem] = Cdw[rr * 80 + rem];
        }
    } else {  // tail tile (j0=2048, jcount=1): 10 bytes per row
        for (int idx = tid; idx < 64 * 10; idx += 256) {
            int rr = idx / 10, n2 = idx - rr * 10;
            BD[((size_t)(lb * 1024 + q0 + rr) * RLD + j0) * 10 + n2] = Call[rr * 320 + n2];
        }
    }
}

// ---------------- MFMA-AC split-K fused attention, 32 q-rows per block -------
// qw_bf/K_bf/V_bf bf16 [b][n][1024][40]; BD fp8 [lb][1024 q][2052 j][10]
// LDS 18.6KB -> 8 blocks/CU. Stride-48 tiles (no K=64 zero pad; chunk2 frag
// is (lane>>4)==0 ? cols32..39 : zero). V staged bf16, cvt in PV.
__global__ __launch_bounds__(256)
void attn7(const ushortt* __restrict__ qwb, const ushortt* __restrict__ Kp,
           const ushortt* __restrict__ Vp, const uchar* __restrict__ BD,
           const int* __restrict__ relpos,
           ushortt* __restrict__ op, float2* __restrict__ ml, int b0, int nb) {
    const int bid = blockIdx.x;
    const int xcd = bid & 7, t = bid >> 3;
    const int gl = t / 10, n = t - gl * 10;
    const int G = gl * 8 + xcd;                // 0 .. 80*nb-1, heavy-first
    int qc, lb, s;
    {
        const int c3 = 32 * nb, c2 = 24 * nb, c1 = 16 * nb;
        if (G < c3)                { qc = 31 - G / (4 * nb); int r2 = G % (4 * nb); lb = r2 >> 2; s = r2 & 3; }
        else if (G < c3 + c2)      { int l2 = G - c3; qc = 23 - l2 / (3 * nb); int r2 = l2 % (3 * nb); lb = r2 / 3; s = r2 % 3; }
        else if (G < c3 + c2 + c1) { int l2 = G - c3 - c2; qc = 15 - l2 / (2 * nb); int r2 = l2 % (2 * nb); lb = r2 >> 1; s = r2 & 1; }
        else                       { int l2 = G - c3 - c2 - c1; qc = 7 - l2 / nb; lb = l2 % nb; s = 0; }
    }
    const int ns = (qc >> 3) + 1;
    const int qbase = qc * 32;
    const int b = b0 + lb;
    const int tid = threadIdx.x;
    const int wid = tid >> 6, lane = tid & 63;
    const int row = tid >> 3, kg = tid & 7;
    const int qi = qbase + row;
    const size_t bn = (size_t)b * NH + n;
    const size_t prow = ((size_t)s * (BSZ * NH) + bn) * 1024 + qi;
    const int ntiles = (qbase + 95) >> 6;

    __shared__ __align__(16) ushortt KtL[64 * 48];   // bf16, cols 0..39 valid
    __shared__ __align__(16) ushortt VtL[64 * 40];   // bf16
    __shared__ __align__(16) ushortt qwL[32 * 48];
    __shared__ __align__(16) ushortt sL[32 * 66];    // AC then p, bf16

    const ushortt* Kbase = Kp + bn * 1024 * 40;
    const ushortt* Vbase = Vp + bn * 1024 * 40;
    const int fr = lane & 15;
    const int kg8 = (lane >> 4) * 8;
    const bool kgz = (lane >> 4) == 0;
    const short8 z8 = {0, 0, 0, 0, 0, 0, 0, 0};

    // block-start: stage qwL (32 x 40 bf16, stride 48)
    for (int e = tid; e < 160; e += 256) {
        int rr = e / 5, cc = (e % 5) * 8;
        *(short8*)&qwL[rr * 48 + cc] = *(const short8*)(qwb + (bn * 1024 + qbase + rr) * 40 + cc);
    }
    float o[5] = {0.f, 0.f, 0.f, 0.f, 0.f};
    float mrun = -INFINITY, lrun = 0.f;
    const int* rp = relpos + ((size_t)b * QLEN + qi) * QLEN;
    const uchar* bdrow = BD + ((size_t)(lb * 1024 + qi)) * (RLD * 10) + n;

    for (int kt = s; kt < ntiles; kt += ns) {
        const int k0 = kt * 64;
        __syncthreads();
        // stage K (stride 48) + V (stride 40), raw bf16
        for (int e = tid; e < 320; e += 256) {
            int rr = e / 5, cc = (e % 5) * 8;
            *(short8*)&KtL[rr * 48 + cc] = *(const short8*)(Kbase + (size_t)(k0 + rr) * 40 + cc);
        }
        for (int e = tid; e < 320; e += 256)
            ((short8*)VtL)[e] = ((const short8*)(Vbase + (size_t)k0 * 40))[e];
        __syncthreads();

        // BD gather (issued early; consumed after MFMA barrier)
        int jv[8];
        #pragma unroll
        for (int ss = 0; ss < 8; ++ss) {
            const int kk = k0 + kg + ss * 8;
            int j = -1;
            if (kk <= qi) {
                int rpv = rp[kk];
                rpv = rpv < -1024 ? -1024 : (rpv > 1024 ? 1024 : rpv);
                j = 1024 - rpv;
            }
            jv[ss] = j;
        }
        float bdv[8];
        #pragma unroll
        for (int ss = 0; ss < 8; ++ss)
            bdv[ss] = (jv[ss] >= 0) ? e4m32f(bdrow[(size_t)jv[ss] * 10]) : 0.f;

        // MFMA: AC[32][64] = qw @ K^T  (wave -> (mt, 2 ct tiles))
        {
            const int mt = wid >> 1, ctb = (wid & 1) * 2;
            short8 a0 = *(const short8*)&qwL[(mt * 16 + fr) * 48 + kg8];
            short8 a1 = kgz ? *(const short8*)&qwL[(mt * 16 + fr) * 48 + 32] : z8;
            #pragma unroll
            for (int c = 0; c < 2; ++c) {
                const int ct = ctb + c;
                short8 b0f = *(const short8*)&KtL[(ct * 16 + fr) * 48 + kg8];
                short8 b1f = kgz ? *(const short8*)&KtL[(ct * 16 + fr) * 48 + 32] : z8;
                float4v acc = {0.f, 0.f, 0.f, 0.f};
                acc = __builtin_amdgcn_mfma_f32_16x16x32_bf16(a0, b0f, acc, 0, 0, 0);
                acc = __builtin_amdgcn_mfma_f32_16x16x32_bf16(a1, b1f, acc, 0, 0, 0);
                #pragma unroll
                for (int j = 0; j < 4; ++j)
                    sL[(mt * 16 + (lane >> 4) * 4 + j) * 66 + ct * 16 + fr] = f2bf(acc[j]);
            }
        }
        __syncthreads();

        // score combine + online softmax
        float sarr[8];
        float pmax = -INFINITY;
        #pragma unroll
        for (int ss = 0; ss < 8; ++ss) {
            float sv = -INFINITY;
            if (jv[ss] >= 0)
                sv = (bf2f(sL[row * 66 + kg + ss * 8]) + bdv[ss]) * SCALE;
            sarr[ss] = sv;
            pmax = fmaxf(pmax, sv);
        }
        pmax = fmaxf(pmax, __shfl_xor(pmax, 1, 64));
        pmax = fmaxf(pmax, __shfl_xor(pmax, 2, 64));
        pmax = fmaxf(pmax, __shfl_xor(pmax, 4, 64));
        const float nm = fmaxf(mrun, pmax);
        const float corr = __expf(mrun - nm);   // first tile: exp(-inf)=0
        float psum = 0.f;
        ushortt* prw = sL + row * 66;
        #pragma unroll
        for (int ss = 0; ss < 8; ++ss) {
            float p = __expf(sarr[ss] - nm);
            psum += p;
            prw[kg + ss * 8] = f2bf(p);
        }
        psum += __shfl_xor(psum, 1, 64);
        psum += __shfl_xor(psum, 2, 64);
        psum += __shfl_xor(psum, 4, 64);
        lrun = lrun * corr + psum;
        mrun = nm;
        #pragma unroll
        for (int jj = 0; jj < 5; ++jj) o[jj] *= corr;
        int kmax = qi - k0 + 1; if (kmax > 64) kmax = 64;
        #pragma unroll 4
        for (int k = 0; k < kmax; ++k) {
            float p = bf2f(prw[k]);
            const ushortt* vr = VtL + k * 40;
            uint2 v4u = *(const uint2*)(vr + 4 * kg);
            o[0] += p * bf2f((ushortt)(v4u.x & 0xffff));
            o[1] += p * bf2f((ushortt)(v4u.x >> 16));
            o[2] += p * bf2f((ushortt)(v4u.y & 0xffff));
            o[3] += p * bf2f((ushortt)(v4u.y >> 16));
            o[4] += p * bf2f(vr[32 + kg]);
        }
    }
    ushortt* oprow = op + prow * 40;
    #pragma unroll
    for (int jj = 0; jj < 4; ++jj) oprow[4 * kg + jj] = f2bf(o[jj]);
    oprow[32 + kg] = f2bf(o[4]);
    if (kg == 0) ml[prow] = make_float2(mrun, lrun);
}

// ---------------- combine split partials -> vec (bf16) ----------------
__global__ __launch_bounds__(256)
void attn_combine(const ushortt* __restrict__ op, const float2* __restrict__ ml,
                  ushortt* __restrict__ vec) {
    const int idx = blockIdx.x * 256 + threadIdx.x;
    if (idx >= BSZ * NH * 1024 * 38) return;
    const int d = idx % 38;
    const int rh = idx / 38;                 // bn*1024 + q
    const int q = rh & 1023;
    const int bn = rh >> 10;
    const int b = bn / NH, n = bn - b * NH;
    const int ns = ((q >> 5) >> 3) + 1;      // splits for this q's chunk
    const size_t stride = (size_t)BSZ * NH * 1024;
    float M = -INFINITY;
    float2 mv[4];
    for (int sp = 0; sp < ns; ++sp) {
        mv[sp] = ml[sp * stride + rh];
        M = fmaxf(M, mv[sp].x);
    }
    float l = 0.f, o = 0.f;
    for (int sp = 0; sp < ns; ++sp) {
        float w = __expf(mv[sp].x - M);
        l += mv[sp].y * w;
        o += bf2f(op[(sp * stride + rh) * 40 + d]) * w;
    }
    vec[((size_t)q * BSZ + b) * 384 + (size_t)n * 38 + d] = f2bf(o / l);
}

// ---------------- residual + LayerNorm ----------------
template<bool WRITE_BF>
__global__ __launch_bounds__(256)
void ln_kernel(const float* __restrict__ x1, const float* __restrict__ x2,
               const float* __restrict__ g, const float* __restrict__ bb,
               float* __restrict__ outf, ushortt* __restrict__ outbf) {
    const int row = blockIdx.x;
    const float* p1 = x1 + (size_t)row * DM;
    const float* p2 = x2 + (size_t)row * DM;
    __shared__ float xb[DM];
    __shared__ float red[256];
    const int tid = threadIdx.x;
    float s = 0.f;
    for (int i = tid; i < DM; i += 256) { float v = p1[i] + p2[i]; xb[i] = v; s += v; }
    red[tid] = s; __syncthreads();
    for (int st = 128; st > 0; st >>= 1) { if (tid < st) red[tid] += red[tid + st]; __syncthreads(); }
    const float mean = red[0] / DM;
    __syncthreads();
    float s2 = 0.f;
    for (int i = tid; i < DM; i += 256) { float d = xb[i] - mean; s2 += d * d; }
    red[tid] = s2; __syncthreads();
    for (int st = 128; st > 0; st >>= 1) { if (tid < st) red[tid] += red[tid + st]; __syncthreads(); }
    const float rstd = rsqrtf(red[0] / DM + 1e-5f);
    for (int i = tid; i < (WRITE_BF ? 384 : DM); i += 256) {
        float v = 0.f;
        if (i < DM) {
            v = (xb[i] - mean) * rstd * g[i] + bb[i];
            outf[(size_t)row * DM + i] = v;
        }
        if (WRITE_BF) outbf[(size_t)row * 384 + i] = f2bf(i < DM ? v : 0.f);
    }
}

extern "C" void kernel_launch(void* const* d_in, const int* in_sizes, int n_in,
                              void* d_out, int out_size, void* d_ws, size_t ws_size,
                              hipStream_t stream) {
    const float* w     = (const float*)d_in[0];
    const float* r     = (const float*)d_in[1];
    const float* rwb   = (const float*)d_in[2];
    const float* rrb   = (const float*)d_in[3];
    const float* qkv_w = (const float*)d_in[4];
    const float* r_w   = (const float*)d_in[5];
    const float* o_w   = (const float*)d_in[6];
    const float* ln1g  = (const float*)d_in[7];
    const float* ln1b  = (const float*)d_in[8];
    const float* ffw1  = (const float*)d_in[9];
    const float* ffb1  = (const float*)d_in[10];
    const float* ffw2  = (const float*)d_in[11];
    const float* ffb2  = (const float*)d_in[12];
    const float* ln2g  = (const float*)d_in[13];
    const float* ln2b  = (const float*)d_in[14];
    const int*   relpos = (const int*)d_in[16];
    float* out = (float*)d_out;

    char* cur = (char*)d_ws;
    auto alloc = [&](size_t bytes) { char* p = cur; cur += (bytes + 255) & ~(size_t)255; return p; };
    ushortt* w_bf    = (ushortt*)alloc((size_t)4096 * 384 * 2);
    ushortt* qkv_bf  = (ushortt*)alloc((size_t)1152 * 384 * 2);
    ushortt* r_bf    = (ushortt*)alloc((size_t)2176 * 384 * 2);
    ushortt* rw_bf   = (ushortt*)alloc((size_t)384 * 384 * 2);
    ushortt* ow_bf   = (ushortt*)alloc((size_t)384 * 384 * 2);
    ushortt* f1_bf   = (ushortt*)alloc((size_t)960 * 384 * 2);
    ushortt* f2_bf   = (ushortt*)alloc((size_t)384 * 928 * 2);
    ushortt* qw_bf   = (ushortt*)alloc((size_t)BSZ * NH * 1024 * 40 * 2);
    ushortt* K_bf    = (ushortt*)alloc((size_t)BSZ * NH * 1024 * 40 * 2);
    ushortt* V_bf    = (ushortt*)alloc((size_t)BSZ * NH * 1024 * 40 * 2);
    ushortt* qr_bf   = (ushortt*)alloc((size_t)BSZ * NH * 1024 * 64 * 2);
    ushortt* rk_bf   = (ushortt*)alloc((size_t)NH * RLP * 64 * 2);
    ushortt* vec_bf  = (ushortt*)alloc((size_t)4096 * 384 * 2);
    ushortt* out1_bf = (ushortt*)alloc((size_t)4096 * 384 * 2);
    ushortt* h1_bf   = (ushortt*)alloc((size_t)4096 * 928 * 2);
    float*   attnf   = (float*)alloc((size_t)4096 * DM * 4);
    float*   out1f   = (float*)alloc((size_t)4096 * DM * 4);
    float*   core    = (float*)alloc((size_t)4096 * DM * 4);

    // split partials alias attnf/out1f/core (dead until after combine):
    ushortt* op_part = (ushortt*)attnf;
    float2*  ml_part = (float2*)((char*)attnf + (size_t)4 * BSZ * NH * 1024 * 40 * 2);

    // BD buffer: fp8 [lb][1024 q][2052 j][10]
    const size_t bd_b_bytes = (size_t)1024 * RLD * 10;   // per-b: ~21 MB
    uchar* BD = (uchar*)alloc(bd_b_bytes * BSZ);
    bool full = ((size_t)(cur - (char*)d_ws) <= ws_size);
    if (!full) { cur = (char*)BD; BD = (uchar*)alloc(bd_b_bytes); }  // per-b reuse

    auto cgrid = [](size_t total) { return dim3((unsigned)((total + 255) / 256)); };
    // fused prologue: all conversions + all pad zeroing, one launch
    prep_all<<<dim3(2048), 256, 0, stream>>>(w, w_bf, qkv_w, qkv_bf, r, r_bf,
                                             r_w, rw_bf, o_w, ow_bf, ffw1, f1_bf, ffw2, f2_bf,
                                             qw_bf, K_bf, V_bf, qr_bf, rk_bf, vec_bf);

    // QKV GEMM with scatter epilogue -> qw_bf / qr_bf / K_bf / V_bf
    gemm_mfma<5><<<dim3(18, 32), 256, 0, stream>>>(w_bf, qkv_bf, rwb, qw_bf, 4096, H3, 384, 0,
                                                   rrb, (float*)qr_bf, (float*)K_bf, (float*)V_bf);
    // rk GEMM -> rk_bf  bf16 [n][2112][64]
    gemm_mfma<6><<<dim3(6, 17), 256, 0, stream>>>(r_bf, rw_bf, nullptr, rk_bf, RLEN, DM, 384, 0,
                                                  nullptr, nullptr, nullptr, nullptr);
    if (full) {
        bd_gemm<<<dim3(65 * 16 * BSZ), 256, 0, stream>>>(qr_bf, rk_bf, BD, 0, BSZ);
        attn7<<<dim3(3200), 256, 0, stream>>>(qw_bf, K_bf, V_bf, BD, relpos,
                                              op_part, ml_part, 0, BSZ);
    } else {
        for (int b = 0; b < BSZ; ++b) {
            bd_gemm<<<dim3(65 * 16), 256, 0, stream>>>(qr_bf, rk_bf, BD, b, 1);
            attn7<<<dim3(800), 256, 0, stream>>>(qw_bf, K_bf, V_bf, BD, relpos,
                                                 op_part, ml_part, b, 1);
        }
    }
    attn_combine<<<cgrid((size_t)BSZ * NH * 1024 * 38), 256, 0, stream>>>(op_part, ml_part, vec_bf);
    // attn_out = vec @ o_w^T   (overwrites op_part alias -- partials are dead)
    gemm_mfma<0><<<dim3(6, 32), 256, 0, stream>>>(vec_bf, ow_bf, nullptr, attnf, 4096, DM, 384, DM,
                                                  nullptr, nullptr, nullptr, nullptr);
    ln_kernel<true><<<4096, 256, 0, stream>>>(w, attnf, ln1g, ln1b, out1f, out1_bf);
    gemm_mfma<3><<<dim3(15, 32), 256, 0, stream>>>(out1_bf, f1_bf, ffb1, h1_bf, 4096, DI, 384, 928,
                                                   nullptr, nullptr, nullptr, nullptr);
    gemm_mfma<4><<<dim3(6, 32), 256, 0, stream>>>(h1_bf, f2_bf, ffb2, core, 4096, DM, 928, DM,
                                                  nullptr, nullptr, nullptr, nullptr);
    ln_kernel<false><<<4096, 256, 0, stream>>>(out1f, core, ln2g, ln2b, out, nullptr);
}